// Round 1
// baseline (590.266 us; speedup 1.0000x reference)
//
#include <hip/hip_runtime.h>
#include <hip/hip_bf16.h>

// DFAChebNet forward, restructured:
//   layer: x@W0 + (agg(x)-x)@W1 + b  ==  x@(W0-W1) + agg(x@W1) + b
// so we project BEFORE the edge scatter (128-wide -> 16-wide traffic).

constexpr int NN   = 100000;
constexpr int NE   = 1600000;
constexpr int FIN  = 128;
constexpr int HID  = 16;
constexpr int NCLS = 32;

__global__ void k_zero(float* __restrict__ p, int n) {
    int i = blockIdx.x * blockDim.x + threadIdx.x;
    if (i < n) p[i] = 0.0f;
}

__global__ void k_deg(const int* __restrict__ row, const float* __restrict__ w,
                      float* __restrict__ deg) {
    int e = blockIdx.x * blockDim.x + threadIdx.x;
    if (e < NE) atomicAdd(&deg[row[e]], w[e]);
}

__global__ void k_dinv(float* __restrict__ deg) {
    int i = blockIdx.x * blockDim.x + threadIdx.x;
    if (i < NN) { float d = deg[i]; deg[i] = d > 0.f ? rsqrtf(d) : 0.f; }
}

__global__ void k_norm(const int* __restrict__ row, const int* __restrict__ col,
                       const float* __restrict__ w, const float* __restrict__ dinv,
                       float* __restrict__ norm) {
    int e = blockIdx.x * blockDim.x + threadIdx.x;
    if (e < NE) norm[e] = dinv[row[e]] * w[e] * dinv[col[e]];
}

// xa = x @ (W1_0 - W1_1) + b1 ; xb = x @ W1_1
// block = 256 threads = 8 nodes x 32 lanes (lane o: o<16 -> xa col o, o>=16 -> xb col o-16)
__global__ __launch_bounds__(256) void k_proj1(
    const float* __restrict__ x, const float* __restrict__ W0,
    const float* __restrict__ W1, const float* __restrict__ b1,
    float* __restrict__ xa, float* __restrict__ xb) {
    __shared__ float Wd[FIN * HID];   // W0 - W1
    __shared__ float Wb[FIN * HID];   // W1
    __shared__ float xs[8 * FIN];
    int tid = threadIdx.x;
    for (int i = tid; i < FIN * HID; i += 256) {
        float w1 = W1[i];
        Wd[i] = W0[i] - w1;
        Wb[i] = w1;
    }
    int nbase = blockIdx.x * 8;
    for (int i = tid; i < 8 * FIN; i += 256) {
        int n = nbase + i / FIN;
        xs[i] = (n < NN) ? x[(long)nbase * FIN + i] : 0.f;
    }
    __syncthreads();
    int nl = tid >> 5;       // 0..7
    int o  = tid & 31;
    int n  = nbase + nl;
    if (n >= NN) return;
    const float* Wp = (o < HID) ? &Wd[o] : &Wb[o - HID];
    const float* xr = &xs[nl * FIN];
    float acc = 0.f;
#pragma unroll 8
    for (int k = 0; k < FIN; k++) acc += xr[k] * Wp[k * HID];
    if (o < HID) xa[n * HID + o] = acc + b1[o];
    else         xb[n * HID + (o - HID)] = acc;
}

// agg1[row] += norm * xb[col], 16 lanes per edge
__global__ void k_scatter1(const int* __restrict__ row, const int* __restrict__ col,
                           const float* __restrict__ norm, const float* __restrict__ xb,
                           float* __restrict__ agg1) {
    long t = (long)blockIdx.x * blockDim.x + threadIdx.x;
    int e = (int)(t >> 4);
    int f = (int)(t & 15);
    if (e >= NE) return;
    float nv = norm[e];
    if (nv == 0.f) return;
    int c = col[e], r = row[e];
    atomicAdd(&agg1[r * HID + f], nv * xb[c * HID + f]);
}

// h = relu(xa + agg1); ha = h@(W2_0-W2_1)+b2 ; hb = h@W2_1
// block = 256 = 4 nodes x 64 lanes (o<32 -> ha, o>=32 -> hb)
__global__ __launch_bounds__(256) void k_proj2(
    const float* __restrict__ xa, const float* __restrict__ agg1,
    const float* __restrict__ W0, const float* __restrict__ W1,
    const float* __restrict__ b2,
    float* __restrict__ ha, float* __restrict__ hb) {
    __shared__ float Wd[HID * NCLS];
    __shared__ float Wb[HID * NCLS];
    int tid = threadIdx.x;
    for (int i = tid; i < HID * NCLS; i += 256) {
        float w1 = W1[i];
        Wd[i] = W0[i] - w1;
        Wb[i] = w1;
    }
    __syncthreads();
    int nl = tid >> 6;       // 0..3
    int o  = tid & 63;
    int n  = blockIdx.x * 4 + nl;
    if (n >= NN) return;
    int oc = o & 31;
    const float* Wp = (o < NCLS) ? &Wd[oc] : &Wb[oc];
    float acc = 0.f;
#pragma unroll
    for (int k = 0; k < HID; k++) {
        float hk = fmaxf(xa[n * HID + k] + agg1[n * HID + k], 0.f);
        acc += hk * Wp[k * NCLS];
    }
    if (o < NCLS) ha[n * NCLS + oc] = acc + b2[oc];
    else          hb[n * NCLS + oc] = acc;
}

// agg2[row] += norm * hb[col], 32 lanes per edge
__global__ void k_scatter2(const int* __restrict__ row, const int* __restrict__ col,
                           const float* __restrict__ norm, const float* __restrict__ hb,
                           float* __restrict__ agg2) {
    long t = (long)blockIdx.x * blockDim.x + threadIdx.x;
    int e = (int)(t >> 5);
    int f = (int)(t & 31);
    if (e >= NE) return;
    float nv = norm[e];
    if (nv == 0.f) return;
    int c = col[e], r = row[e];
    atomicAdd(&agg2[r * NCLS + f], nv * hb[c * NCLS + f]);
}

// out = log_softmax(ha + agg2) rowwise (32 classes, 32 lanes per node)
__global__ void k_lsm(const float* __restrict__ ha, const float* __restrict__ agg2,
                      float* __restrict__ out) {
    long t = (long)blockIdx.x * blockDim.x + threadIdx.x;
    int n = (int)(t >> 5);
    int f = (int)(t & 31);
    if (n >= NN) return;
    float v = ha[n * NCLS + f] + agg2[n * NCLS + f];
    float m = v;
    for (int s = 16; s > 0; s >>= 1) m = fmaxf(m, __shfl_xor(m, s, 32));
    float ex = __expf(v - m);
    float sum = ex;
    for (int s = 16; s > 0; s >>= 1) sum += __shfl_xor(sum, s, 32);
    out[n * NCLS + f] = (v - m) - logf(sum);
}

extern "C" void kernel_launch(void* const* d_in, const int* in_sizes, int n_in,
                              void* d_out, int out_size, void* d_ws, size_t ws_size,
                              hipStream_t stream) {
    const float* x    = (const float*)d_in[0];
    const int*   ei   = (const int*)d_in[1];   // [2, E] int32
    const float* ew   = (const float*)d_in[2];
    const float* W1_0 = (const float*)d_in[3];
    const float* W1_1 = (const float*)d_in[4];
    const float* b1   = (const float*)d_in[5];
    const float* W2_0 = (const float*)d_in[6];
    const float* W2_1 = (const float*)d_in[7];
    const float* b2   = (const float*)d_in[8];
    float* out = (float*)d_out;

    const int* row = ei;
    const int* col = ei + NE;

    // workspace layout (floats); zero-region [deg|agg1|agg2] is contiguous
    float* ws   = (float*)d_ws;
    float* deg  = ws;                      // NN
    float* agg1 = deg  + NN;               // NN*HID
    float* agg2 = agg1 + (long)NN * HID;   // NN*NCLS
    float* norm = agg2 + (long)NN * NCLS;  // NE
    float* xa   = norm + NE;               // NN*HID
    float* xb   = xa   + (long)NN * HID;   // NN*HID
    float* ha   = xb   + (long)NN * HID;   // NN*NCLS
    float* hb   = ha   + (long)NN * NCLS;  // NN*NCLS

    int zn = NN * (1 + HID + NCLS);
    k_zero<<<(zn + 255) / 256, 256, 0, stream>>>(deg, zn);
    k_deg<<<(NE + 255) / 256, 256, 0, stream>>>(row, ew, deg);
    k_dinv<<<(NN + 255) / 256, 256, 0, stream>>>(deg);
    k_norm<<<(NE + 255) / 256, 256, 0, stream>>>(row, col, ew, deg, norm);
    k_proj1<<<(NN + 7) / 8, 256, 0, stream>>>(x, W1_0, W1_1, b1, xa, xb);
    {
        long th = (long)NE * HID;
        k_scatter1<<<(int)((th + 255) / 256), 256, 0, stream>>>(row, col, norm, xb, agg1);
    }
    k_proj2<<<(NN + 3) / 4, 256, 0, stream>>>(xa, agg1, W2_0, W2_1, b2, ha, hb);
    {
        long th = (long)NE * NCLS;
        k_scatter2<<<(int)((th + 255) / 256), 256, 0, stream>>>(row, col, norm, hb, agg2);
    }
    {
        long th = (long)NN * NCLS;
        k_lsm<<<(int)((th + 255) / 256), 256, 0, stream>>>(ha, agg2, out);
    }
}

// Round 2
// 506.982 us; speedup vs baseline: 1.1643x; 1.1643x over previous
//
#include <hip/hip_runtime.h>
#include <hip/hip_bf16.h>

// DFAChebNet forward. Restructuring:
//  layer: x@W0 + (agg(x)-x)@W1 + b == x@(W0-W1) + agg(x@W1) + b   (project first)
//  aggregation: CSR pull-gather (build CSR per call) instead of float atomics
//  (device-scope float atomicAdd writes through to HBM per-op: 200 MB WRITE_SIZE).

constexpr int NN   = 100000;
constexpr int NE   = 1600000;
constexpr int FIN  = 128;
constexpr int HID  = 16;
constexpr int NCLS = 32;
constexpr int SCAN_CHUNK = 512;
constexpr int NB_SCAN = (NN + SCAN_CHUNK - 1) / SCAN_CHUNK;  // 196

__global__ void k_zero_int(int* __restrict__ p, int n) {
    int i = blockIdx.x * blockDim.x + threadIdx.x;
    if (i < n) p[i] = 0;
}

__global__ void k_count(const int* __restrict__ row, int* __restrict__ count) {
    int e = blockIdx.x * blockDim.x + threadIdx.x;
    if (e < NE) atomicAdd(&count[row[e]], 1);
}

// block-level exclusive scan of count -> rowptr (local), block totals -> bsum
__global__ __launch_bounds__(SCAN_CHUNK) void k_scan_block(
    const int* __restrict__ count, int* __restrict__ rowptr, int* __restrict__ bsum) {
    __shared__ int sh[SCAN_CHUNK];
    int tid = threadIdx.x;
    int i = blockIdx.x * SCAN_CHUNK + tid;
    int v = (i < NN) ? count[i] : 0;
    sh[tid] = v;
    __syncthreads();
    for (int off = 1; off < SCAN_CHUNK; off <<= 1) {
        int t = (tid >= off) ? sh[tid - off] : 0;
        __syncthreads();
        sh[tid] += t;
        __syncthreads();
    }
    if (i < NN) rowptr[i] = sh[tid] - v;          // exclusive
    if (tid == SCAN_CHUNK - 1) bsum[blockIdx.x] = sh[tid];
}

// exclusive scan of bsum (<= 256 entries), single wave
__global__ void k_scan_tops(int* __restrict__ bsum, int nb) {
    int lane = threadIdx.x;  // 64 threads
    int v[4], e[4];
    int s = 0;
#pragma unroll
    for (int t = 0; t < 4; t++) {
        int idx = lane * 4 + t;
        v[t] = (idx < nb) ? bsum[idx] : 0;
        e[t] = s;
        s += v[t];
    }
    int sc = s;
    for (int off = 1; off < 64; off <<= 1) {
        int up = __shfl_up(sc, off, 64);
        if (lane >= off) sc += up;
    }
    int excl = sc - s;
#pragma unroll
    for (int t = 0; t < 4; t++) {
        int idx = lane * 4 + t;
        if (idx < nb) bsum[idx] = excl + e[t];
    }
}

__global__ void k_scan_add(int* __restrict__ rowptr, const int* __restrict__ bsum,
                           int* __restrict__ cursor) {
    int i = blockIdx.x * blockDim.x + threadIdx.x;
    if (i < NN) {
        rowptr[i] += bsum[i >> 9];   // 512 = 2^9
        cursor[i] = 0;
        if (i == 0) rowptr[NN] = NE;
    }
}

__global__ void k_edgescatter(const int* __restrict__ row, const int* __restrict__ col,
                              const float* __restrict__ w, const int* __restrict__ rowptr,
                              int* __restrict__ cursor,
                              int* __restrict__ colS, float* __restrict__ wS) {
    int e = blockIdx.x * blockDim.x + threadIdx.x;
    if (e >= NE) return;
    int r = row[e];
    int pos = rowptr[r] + atomicAdd(&cursor[r], 1);
    colS[pos] = col[e];
    wS[pos]   = w[e];
}

// dinv[n] = rsqrt(sum of wS over node n's bucket)
__global__ void k_dinv(const int* __restrict__ rowptr, const float* __restrict__ wS,
                       float* __restrict__ dinv) {
    int n = blockIdx.x * blockDim.x + threadIdx.x;
    if (n >= NN) return;
    int s = rowptr[n], e = rowptr[n + 1];
    float d = 0.f;
    for (int j = s; j < e; j++) d += wS[j];
    dinv[n] = d > 0.f ? rsqrtf(d) : 0.f;
}

// xa = x@(W1_0-W1_1)+b1 ; xb = x@W1_1.  1 thread = 1 node, 32 accumulators.
// x staged in LDS (stride 33: conflict-free), W via wave-uniform loads (s_load).
__global__ __launch_bounds__(256) void k_proj1(
    const float* __restrict__ x, const float* __restrict__ W0,
    const float* __restrict__ W1, const float* __restrict__ b1,
    float* __restrict__ xa, float* __restrict__ xb) {
    __shared__ float xs[256 * 33];
    int tid = threadIdx.x;
    long nbase = (long)blockIdx.x * 256;
    float accA[HID], accB[HID];
#pragma unroll
    for (int o = 0; o < HID; o++) { accA[o] = 0.f; accB[o] = 0.f; }
    const float4* xg = (const float4*)x;  // node stride = 32 float4
    for (int c = 0; c < 4; c++) {
#pragma unroll
        for (int i = 0; i < 8; i++) {
            int j = i * 256 + tid;          // 0..2047
            int node = j >> 3, w4 = j & 7;  // 8 float4 per node-chunk
            long gn = nbase + node;
            float4 v = make_float4(0.f, 0.f, 0.f, 0.f);
            if (gn < NN) v = xg[gn * 32 + c * 8 + w4];
            int base = node * 33 + w4 * 4;
            xs[base + 0] = v.x; xs[base + 1] = v.y;
            xs[base + 2] = v.z; xs[base + 3] = v.w;
        }
        __syncthreads();
#pragma unroll 4
        for (int kk = 0; kk < 32; kk++) {
            float xk = xs[tid * 33 + kk];
            int k = c * 32 + kk;
#pragma unroll
            for (int o = 0; o < HID; o++) accA[o] += xk * W0[k * HID + o];
#pragma unroll
            for (int o = 0; o < HID; o++) accB[o] += xk * W1[k * HID + o];
        }
        __syncthreads();
    }
    long n = nbase + tid;
    if (n >= NN) return;
    float4* xap = (float4*)(xa + n * HID);
    float4* xbp = (float4*)(xb + n * HID);
#pragma unroll
    for (int q = 0; q < 4; q++) {
        float4 va, vb;
        va.x = accA[4*q+0] - accB[4*q+0] + b1[4*q+0];
        va.y = accA[4*q+1] - accB[4*q+1] + b1[4*q+1];
        va.z = accA[4*q+2] - accB[4*q+2] + b1[4*q+2];
        va.w = accA[4*q+3] - accB[4*q+3] + b1[4*q+3];
        vb.x = accB[4*q+0]; vb.y = accB[4*q+1];
        vb.z = accB[4*q+2]; vb.w = accB[4*q+3];
        xap[q] = va; xbp[q] = vb;
    }
}

// agg1[n,f] = sum_j dinv[n]*wS[j]*dinv[colS[j]] * xb[colS[j],f]; 16 lanes/node
__global__ __launch_bounds__(256) void k_gather1(
    const int* __restrict__ rowptr, const int* __restrict__ colS,
    const float* __restrict__ wS, const float* __restrict__ dinv,
    const float* __restrict__ xb, float* __restrict__ agg1) {
    long t = (long)blockIdx.x * 256 + threadIdx.x;
    int n = (int)(t >> 4), f = (int)(t & 15);
    if (n >= NN) return;
    int s = rowptr[n], e = rowptr[n + 1];
    float dn = dinv[n];
    float acc = 0.f;
    for (int j = s; j < e; j++) {
        int c = colS[j];
        float nv = dn * wS[j] * dinv[c];
        acc += nv * xb[c * HID + f];
    }
    agg1[n * HID + f] = acc;
}

// h = relu(xa+agg1); ha = h@(W2_0-W2_1)+b2 ; hb = h@W2_1.  1 thread = 1 node.
__global__ __launch_bounds__(256) void k_proj2(
    const float* __restrict__ xa, const float* __restrict__ agg1,
    const float* __restrict__ W0, const float* __restrict__ W1,
    const float* __restrict__ b2,
    float* __restrict__ ha, float* __restrict__ hb) {
    long n = (long)blockIdx.x * 256 + threadIdx.x;
    if (n >= NN) return;
    float h[HID];
    const float4* xap = (const float4*)(xa + n * HID);
    const float4* agp = (const float4*)(agg1 + n * HID);
#pragma unroll
    for (int q = 0; q < 4; q++) {
        float4 a = xap[q], g = agp[q];
        h[4*q+0] = fmaxf(a.x + g.x, 0.f);
        h[4*q+1] = fmaxf(a.y + g.y, 0.f);
        h[4*q+2] = fmaxf(a.z + g.z, 0.f);
        h[4*q+3] = fmaxf(a.w + g.w, 0.f);
    }
    float accA[NCLS], accB[NCLS];
#pragma unroll
    for (int o = 0; o < NCLS; o++) { accA[o] = 0.f; accB[o] = 0.f; }
#pragma unroll 2
    for (int k = 0; k < HID; k++) {
        float hk = h[k];
#pragma unroll
        for (int o = 0; o < NCLS; o++) accA[o] += hk * W0[k * NCLS + o];
#pragma unroll
        for (int o = 0; o < NCLS; o++) accB[o] += hk * W1[k * NCLS + o];
    }
    float4* hap = (float4*)(ha + n * NCLS);
    float4* hbp = (float4*)(hb + n * NCLS);
#pragma unroll
    for (int q = 0; q < 8; q++) {
        float4 va, vb;
        va.x = accA[4*q+0] - accB[4*q+0] + b2[4*q+0];
        va.y = accA[4*q+1] - accB[4*q+1] + b2[4*q+1];
        va.z = accA[4*q+2] - accB[4*q+2] + b2[4*q+2];
        va.w = accA[4*q+3] - accB[4*q+3] + b2[4*q+3];
        vb.x = accB[4*q+0]; vb.y = accB[4*q+1];
        vb.z = accB[4*q+2]; vb.w = accB[4*q+3];
        hap[q] = va; hbp[q] = vb;
    }
}

// out[n,:] = log_softmax(ha[n,:] + gather(hb)); 32 lanes/node, fused softmax
__global__ __launch_bounds__(256) void k_gather2_lsm(
    const int* __restrict__ rowptr, const int* __restrict__ colS,
    const float* __restrict__ wS, const float* __restrict__ dinv,
    const float* __restrict__ ha, const float* __restrict__ hb,
    float* __restrict__ out) {
    long t = (long)blockIdx.x * 256 + threadIdx.x;
    int n = (int)(t >> 5), o = (int)(t & 31);
    if (n >= NN) return;
    int s = rowptr[n], e = rowptr[n + 1];
    float dn = dinv[n];
    float acc = ha[n * NCLS + o];
    for (int j = s; j < e; j++) {
        int c = colS[j];
        float nv = dn * wS[j] * dinv[c];
        acc += nv * hb[c * NCLS + o];
    }
    float m = acc;
    for (int sh = 16; sh > 0; sh >>= 1) m = fmaxf(m, __shfl_xor(m, sh, 32));
    float ex = __expf(acc - m);
    float sum = ex;
    for (int sh = 16; sh > 0; sh >>= 1) sum += __shfl_xor(sum, sh, 32);
    out[n * NCLS + o] = (acc - m) - logf(sum);
}

extern "C" void kernel_launch(void* const* d_in, const int* in_sizes, int n_in,
                              void* d_out, int out_size, void* d_ws, size_t ws_size,
                              hipStream_t stream) {
    const float* x    = (const float*)d_in[0];
    const int*   ei   = (const int*)d_in[1];
    const float* ew   = (const float*)d_in[2];
    const float* W1_0 = (const float*)d_in[3];
    const float* W1_1 = (const float*)d_in[4];
    const float* b1   = (const float*)d_in[5];
    const float* W2_0 = (const float*)d_in[6];
    const float* W2_1 = (const float*)d_in[7];
    const float* b2   = (const float*)d_in[8];
    float* out = (float*)d_out;

    const int* row = ei;
    const int* col = ei + NE;

    char* ws = (char*)d_ws;
    int*   count  = (int*)ws;                    ws += sizeof(int) * NN;
    int*   cursor = (int*)ws;                    ws += sizeof(int) * NN;
    int*   bsum   = (int*)ws;                    ws += sizeof(int) * 256;
    int*   rowptr = (int*)ws;                    ws += sizeof(int) * (NN + 1);
    int*   colS   = (int*)ws;                    ws += sizeof(int) * NE;
    float* wS     = (float*)ws;                  ws += sizeof(float) * NE;
    float* dinv   = (float*)ws;                  ws += sizeof(float) * NN;
    float* xa     = (float*)ws;                  ws += sizeof(float) * NN * HID;
    float* xb     = (float*)ws;                  ws += sizeof(float) * NN * HID;
    float* agg1   = (float*)ws;                  ws += sizeof(float) * NN * HID;
    float* ha     = (float*)ws;                  ws += sizeof(float) * NN * NCLS;
    float* hb     = (float*)ws;                  ws += sizeof(float) * NN * NCLS;

    k_zero_int<<<(NN + 255) / 256, 256, 0, stream>>>(count, NN);
    k_count<<<(NE + 255) / 256, 256, 0, stream>>>(row, count);
    k_scan_block<<<NB_SCAN, SCAN_CHUNK, 0, stream>>>(count, rowptr, bsum);
    k_scan_tops<<<1, 64, 0, stream>>>(bsum, NB_SCAN);
    k_scan_add<<<(NN + 255) / 256, 256, 0, stream>>>(rowptr, bsum, cursor);
    k_edgescatter<<<(NE + 255) / 256, 256, 0, stream>>>(row, col, ew, rowptr, cursor, colS, wS);
    k_dinv<<<(NN + 255) / 256, 256, 0, stream>>>(rowptr, wS, dinv);
    k_proj1<<<(NN + 255) / 256, 256, 0, stream>>>(x, W1_0, W1_1, b1, xa, xb);
    k_gather1<<<(NN * 16 + 255) / 256, 256, 0, stream>>>(rowptr, colS, wS, dinv, xb, agg1);
    k_proj2<<<(NN + 255) / 256, 256, 0, stream>>>(xa, agg1, W2_0, W2_1, b2, ha, hb);
    k_gather2_lsm<<<(NN * 32 + 255) / 256, 256, 0, stream>>>(rowptr, colS, wS, dinv, ha, hb, out);
}

// Round 3
// 393.661 us; speedup vs baseline: 1.4994x; 1.2879x over previous
//
#include <hip/hip_runtime.h>
#include <hip/hip_bf16.h>

// DFAChebNet forward.
//  layer: x@W0 + (agg(x)-x)@W1 + b == x@(W0-W1) + agg(x@W1) + b   (project first)
//  aggregation: CSR pull-gather. CSR built with a two-level LDS-staged counting
//  sort (coalesced global writes) -- scattered 4B stores / atomics write ~48B
//  to HBM each (R1: 200MB, R2: 154MB WRITE_SIZE), so all scatter goes via LDS.

constexpr int NN   = 100000;
constexpr int NE   = 1600000;
constexpr int FIN  = 128;
constexpr int HID  = 16;
constexpr int NCLS = 32;

constexpr int RB    = 256;                         // rows per bucket
constexpr int NBKT  = (NN + RB - 1) / RB;          // 391
constexpr int EPB   = 8192;                        // edges per partition block
constexpr int GP    = (NE + EPB - 1) / EPB;        // 196
constexpr int NTOT  = NBKT * GP;                   // 76636
constexpr int SCAN_CHUNK = 512;
constexpr int NBS   = (NTOT + SCAN_CHUNK - 1) / SCAN_CHUNK;  // 150
constexpr int CAP   = 8192;                        // bucket edge cap (mean 4096)

// ---- pass A: per-block bucket histogram (bucket-major output) ----
__global__ __launch_bounds__(256) void k_hist(const int* __restrict__ row,
                                              int* __restrict__ blockhist) {
    __shared__ int hist[NBKT];
    int tid = threadIdx.x;
    for (int i = tid; i < NBKT; i += 256) hist[i] = 0;
    __syncthreads();
    long ebase = (long)blockIdx.x * EPB;
#pragma unroll
    for (int i = 0; i < EPB / 256; i++) {
        long e = ebase + i * 256 + tid;
        if (e < NE) atomicAdd(&hist[row[e] >> 8], 1);
    }
    __syncthreads();
    for (int i = tid; i < NBKT; i += 256)
        blockhist[i * GP + blockIdx.x] = hist[i];
}

// ---- scan machinery (length-n exclusive scan, chunk 512) ----
__global__ __launch_bounds__(SCAN_CHUNK) void k_scan_block(
    const int* __restrict__ in, int* __restrict__ outExcl,
    int* __restrict__ bsum, int n) {
    __shared__ int sh[SCAN_CHUNK];
    int tid = threadIdx.x;
    int i = blockIdx.x * SCAN_CHUNK + tid;
    int v = (i < n) ? in[i] : 0;
    sh[tid] = v;
    __syncthreads();
    for (int off = 1; off < SCAN_CHUNK; off <<= 1) {
        int t = (tid >= off) ? sh[tid - off] : 0;
        __syncthreads();
        sh[tid] += t;
        __syncthreads();
    }
    if (i < n) outExcl[i] = sh[tid] - v;
    if (tid == SCAN_CHUNK - 1) bsum[blockIdx.x] = sh[tid];
}

__global__ void k_scan_tops(int* __restrict__ bsum, int nb) {
    int lane = threadIdx.x;  // 64 threads
    int v[4], e[4];
    int s = 0;
#pragma unroll
    for (int t = 0; t < 4; t++) {
        int idx = lane * 4 + t;
        v[t] = (idx < nb) ? bsum[idx] : 0;
        e[t] = s;
        s += v[t];
    }
    int sc = s;
    for (int off = 1; off < 64; off <<= 1) {
        int up = __shfl_up(sc, off, 64);
        if (lane >= off) sc += up;
    }
    int excl = sc - s;
#pragma unroll
    for (int t = 0; t < 4; t++) {
        int idx = lane * 4 + t;
        if (idx < nb) bsum[idx] = excl + e[t];
    }
}

__global__ void k_scan_add(int* __restrict__ outExcl, const int* __restrict__ bsum, int n) {
    int i = blockIdx.x * blockDim.x + threadIdx.x;
    if (i < n) outExcl[i] += bsum[i >> 9];
}

// ---- pass B: LDS-staged partition by bucket, coalesced global writes ----
__global__ __launch_bounds__(256) void k_partition(
    const int* __restrict__ row, const int* __restrict__ col,
    const float* __restrict__ w, const int* __restrict__ scanExcl,
    int2* __restrict__ part) {
    __shared__ int2 stage[EPB];          // 64KB
    __shared__ int cnt[NBKT];
    __shared__ int lofs[NBKT];
    __shared__ int cursor[NBKT];
    __shared__ int gbase[NBKT];
    __shared__ int sa[512], sb[512];
    int tid = threadIdx.x;
    long ebase = (long)blockIdx.x * EPB;
    for (int i = tid; i < NBKT; i += 256) cnt[i] = 0;
    __syncthreads();
#pragma unroll
    for (int i = 0; i < EPB / 256; i++) {
        long e = ebase + i * 256 + tid;
        if (e < NE) atomicAdd(&cnt[row[e] >> 8], 1);
    }
    __syncthreads();
    // exclusive scan of cnt (391) via Hillis-Steele over 512 padded slots
    for (int i = tid; i < 512; i += 256) sa[i] = (i < NBKT) ? cnt[i] : 0;
    __syncthreads();
    int* src = sa; int* dst = sb;
    for (int off = 1; off < 512; off <<= 1) {
        for (int i = tid; i < 512; i += 256)
            dst[i] = src[i] + ((i >= off) ? src[i - off] : 0);
        __syncthreads();
        int* t = src; src = dst; dst = t;
    }
    for (int i = tid; i < NBKT; i += 256) {
        int ex = src[i] - cnt[i];
        lofs[i] = ex;
        cursor[i] = ex;
        gbase[i] = scanExcl[i * GP + blockIdx.x];
    }
    __syncthreads();
    // place into LDS stage, bucket-grouped
#pragma unroll
    for (int i = 0; i < EPB / 256; i++) {
        long e = ebase + i * 256 + tid;
        if (e < NE) {
            int r = row[e];
            int b = r >> 8;
            int p = atomicAdd(&cursor[b], 1);
            int2 v;
            v.x = col[e] | ((r & 255) << 17);   // col<2^17, rowlow in bits 17..24
            v.y = __float_as_int(w[e]);
            stage[p] = v;
        }
    }
    __syncthreads();
    int total = (int)min((long)EPB, NE - ebase);
    for (int i = tid; i < total; i += 256) {
        // bucket of staged index i = largest b with lofs[b] <= i
        int lo = 0, hi = NBKT - 1;
        while (lo < hi) {
            int mid = (lo + hi + 1) >> 1;
            if (lofs[mid] <= i) lo = mid; else hi = mid - 1;
        }
        part[gbase[lo] + (i - lofs[lo])] = stage[i];
    }
}

// ---- pass C: in-place per-bucket sort by row, emits rowptr ----
__global__ __launch_bounds__(256) void k_bucket_sort(
    int2* __restrict__ part, const int* __restrict__ scanExcl,
    int* __restrict__ rowptr) {
    __shared__ int2 stage[CAP];          // 64KB
    __shared__ int hist[RB];
    __shared__ int cursor[RB];
    __shared__ int wtot[4];
    int b = blockIdx.x;
    int tid = threadIdx.x;
    int start = scanExcl[b * GP];
    int end = (b + 1 < NBKT) ? scanExcl[(b + 1) * GP] : NE;
    int count = end - start;
    hist[tid] = 0;
    __syncthreads();
    for (int i = tid; i < count; i += 256)
        atomicAdd(&hist[(part[start + i].x >> 17) & 255], 1);
    __syncthreads();
    // exclusive scan of hist[256]: wave shfl scan + wave totals
    int lane = tid & 63, wv = tid >> 6;
    int v = hist[tid];
    int sc = v;
#pragma unroll
    for (int off = 1; off < 64; off <<= 1) {
        int up = __shfl_up(sc, off, 64);
        if (lane >= off) sc += up;
    }
    if (lane == 63) wtot[wv] = sc;
    __syncthreads();
    int add = 0;
    for (int w2 = 0; w2 < wv; w2++) add += wtot[w2];
    int ex = sc + add - v;
    int node = b * RB + tid;
    if (node <= NN) rowptr[node] = start + ex;   // node==NN lands here (last bucket)
    cursor[tid] = ex;
    __syncthreads();
    for (int i = tid; i < count; i += 256) {
        int2 p = part[start + i];
        int rl = (p.x >> 17) & 255;
        int pos = atomicAdd(&cursor[rl], 1);
        int2 c; c.x = p.x & 0x1FFFF; c.y = p.y;
        if (pos < CAP) stage[pos] = c;
    }
    __syncthreads();
    for (int i = tid; i < count; i += 256)
        if (i < CAP) part[start + i] = stage[i];
}

// dinv[n] = rsqrt(sum of w over node n's bucket)
__global__ void k_dinv(const int* __restrict__ rowptr, const int2* __restrict__ part,
                       float* __restrict__ dinv) {
    int n = blockIdx.x * blockDim.x + threadIdx.x;
    if (n >= NN) return;
    int s = rowptr[n], e = rowptr[n + 1];
    float d = 0.f;
    for (int j = s; j < e; j++) d += __int_as_float(part[j].y);
    dinv[n] = d > 0.f ? rsqrtf(d) : 0.f;
}

// xa = x@(W1_0-W1_1)+b1 ; xb = x@W1_1.  1 thread = 1 node, 32 accumulators.
__global__ __launch_bounds__(256) void k_proj1(
    const float* __restrict__ x, const float* __restrict__ W0,
    const float* __restrict__ W1, const float* __restrict__ b1,
    float* __restrict__ xa, float* __restrict__ xb) {
    __shared__ float xs[256 * 33];
    int tid = threadIdx.x;
    long nbase = (long)blockIdx.x * 256;
    float accA[HID], accB[HID];
#pragma unroll
    for (int o = 0; o < HID; o++) { accA[o] = 0.f; accB[o] = 0.f; }
    const float4* xg = (const float4*)x;  // node stride = 32 float4
    for (int c = 0; c < 4; c++) {
#pragma unroll
        for (int i = 0; i < 8; i++) {
            int j = i * 256 + tid;
            int node = j >> 3, w4 = j & 7;
            long gn = nbase + node;
            float4 v = make_float4(0.f, 0.f, 0.f, 0.f);
            if (gn < NN) v = xg[gn * 32 + c * 8 + w4];
            int base = node * 33 + w4 * 4;
            xs[base + 0] = v.x; xs[base + 1] = v.y;
            xs[base + 2] = v.z; xs[base + 3] = v.w;
        }
        __syncthreads();
#pragma unroll 4
        for (int kk = 0; kk < 32; kk++) {
            float xk = xs[tid * 33 + kk];
            int k = c * 32 + kk;
#pragma unroll
            for (int o = 0; o < HID; o++) accA[o] += xk * W0[k * HID + o];
#pragma unroll
            for (int o = 0; o < HID; o++) accB[o] += xk * W1[k * HID + o];
        }
        __syncthreads();
    }
    long n = nbase + tid;
    if (n >= NN) return;
    float4* xap = (float4*)(xa + n * HID);
    float4* xbp = (float4*)(xb + n * HID);
#pragma unroll
    for (int q = 0; q < 4; q++) {
        float4 va, vb;
        va.x = accA[4*q+0] - accB[4*q+0] + b1[4*q+0];
        va.y = accA[4*q+1] - accB[4*q+1] + b1[4*q+1];
        va.z = accA[4*q+2] - accB[4*q+2] + b1[4*q+2];
        va.w = accA[4*q+3] - accB[4*q+3] + b1[4*q+3];
        vb.x = accB[4*q+0]; vb.y = accB[4*q+1];
        vb.z = accB[4*q+2]; vb.w = accB[4*q+3];
        xap[q] = va; xbp[q] = vb;
    }
}

// agg1[n,f] = sum_j dn*w*dinv[c] * xb[c,f]; 16 lanes/node
__global__ __launch_bounds__(256) void k_gather1(
    const int* __restrict__ rowptr, const int2* __restrict__ part,
    const float* __restrict__ dinv, const float* __restrict__ xb,
    float* __restrict__ agg1) {
    long t = (long)blockIdx.x * 256 + threadIdx.x;
    int n = (int)(t >> 4), f = (int)(t & 15);
    if (n >= NN) return;
    int s = rowptr[n], e = rowptr[n + 1];
    float dn = dinv[n];
    float acc = 0.f;
    for (int j = s; j < e; j++) {
        int2 ed = part[j];
        int c = ed.x;
        float nv = dn * __int_as_float(ed.y) * dinv[c];
        acc += nv * xb[c * HID + f];
    }
    agg1[n * HID + f] = acc;
}

// h = relu(xa+agg1); ha = h@(W2_0-W2_1)+b2 ; hb = h@W2_1.  1 thread = 1 node.
__global__ __launch_bounds__(256) void k_proj2(
    const float* __restrict__ xa, const float* __restrict__ agg1,
    const float* __restrict__ W0, const float* __restrict__ W1,
    const float* __restrict__ b2,
    float* __restrict__ ha, float* __restrict__ hb) {
    long n = (long)blockIdx.x * 256 + threadIdx.x;
    if (n >= NN) return;
    float h[HID];
    const float4* xap = (const float4*)(xa + n * HID);
    const float4* agp = (const float4*)(agg1 + n * HID);
#pragma unroll
    for (int q = 0; q < 4; q++) {
        float4 a = xap[q], g = agp[q];
        h[4*q+0] = fmaxf(a.x + g.x, 0.f);
        h[4*q+1] = fmaxf(a.y + g.y, 0.f);
        h[4*q+2] = fmaxf(a.z + g.z, 0.f);
        h[4*q+3] = fmaxf(a.w + g.w, 0.f);
    }
    float accA[NCLS], accB[NCLS];
#pragma unroll
    for (int o = 0; o < NCLS; o++) { accA[o] = 0.f; accB[o] = 0.f; }
#pragma unroll 2
    for (int k = 0; k < HID; k++) {
        float hk = h[k];
#pragma unroll
        for (int o = 0; o < NCLS; o++) accA[o] += hk * W0[k * NCLS + o];
#pragma unroll
        for (int o = 0; o < NCLS; o++) accB[o] += hk * W1[k * NCLS + o];
    }
    float4* hap = (float4*)(ha + n * NCLS);
    float4* hbp = (float4*)(hb + n * NCLS);
#pragma unroll
    for (int q = 0; q < 8; q++) {
        float4 va, vb;
        va.x = accA[4*q+0] - accB[4*q+0] + b2[4*q+0];
        va.y = accA[4*q+1] - accB[4*q+1] + b2[4*q+1];
        va.z = accA[4*q+2] - accB[4*q+2] + b2[4*q+2];
        va.w = accA[4*q+3] - accB[4*q+3] + b2[4*q+3];
        vb.x = accB[4*q+0]; vb.y = accB[4*q+1];
        vb.z = accB[4*q+2]; vb.w = accB[4*q+3];
        hap[q] = va; hbp[q] = vb;
    }
}

// out[n,:] = log_softmax(ha[n,:] + gather(hb)); 32 lanes/node
__global__ __launch_bounds__(256) void k_gather2_lsm(
    const int* __restrict__ rowptr, const int2* __restrict__ part,
    const float* __restrict__ dinv, const float* __restrict__ ha,
    const float* __restrict__ hb, float* __restrict__ out) {
    long t = (long)blockIdx.x * 256 + threadIdx.x;
    int n = (int)(t >> 5), o = (int)(t & 31);
    if (n >= NN) return;
    int s = rowptr[n], e = rowptr[n + 1];
    float dn = dinv[n];
    float acc = ha[n * NCLS + o];
    for (int j = s; j < e; j++) {
        int2 ed = part[j];
        int c = ed.x;
        float nv = dn * __int_as_float(ed.y) * dinv[c];
        acc += nv * hb[c * NCLS + o];
    }
    float m = acc;
    for (int sh = 16; sh > 0; sh >>= 1) m = fmaxf(m, __shfl_xor(m, sh, 32));
    float ex2 = __expf(acc - m);
    float sum = ex2;
    for (int sh = 16; sh > 0; sh >>= 1) sum += __shfl_xor(sum, sh, 32);
    out[n * NCLS + o] = (acc - m) - logf(sum);
}

extern "C" void kernel_launch(void* const* d_in, const int* in_sizes, int n_in,
                              void* d_out, int out_size, void* d_ws, size_t ws_size,
                              hipStream_t stream) {
    const float* x    = (const float*)d_in[0];
    const int*   ei   = (const int*)d_in[1];
    const float* ew   = (const float*)d_in[2];
    const float* W1_0 = (const float*)d_in[3];
    const float* W1_1 = (const float*)d_in[4];
    const float* b1   = (const float*)d_in[5];
    const float* W2_0 = (const float*)d_in[6];
    const float* W2_1 = (const float*)d_in[7];
    const float* b2   = (const float*)d_in[8];
    float* out = (float*)d_out;

    const int* row = ei;
    const int* col = ei + NE;

    char* ws = (char*)d_ws;                       // 8B-aligned base
    int2*  part      = (int2*)ws;                 ws += sizeof(int2) * NE;
    int*   blockhist = (int*)ws;                  ws += sizeof(int) * NTOT;
    int*   scanExcl  = (int*)ws;                  ws += sizeof(int) * NTOT;
    int*   bsum      = (int*)ws;                  ws += sizeof(int) * 256;
    int*   rowptr    = (int*)ws;                  ws += sizeof(int) * (NN + 1);
    float* dinv      = (float*)ws;                ws += sizeof(float) * NN;
    float* xa        = (float*)ws;                ws += sizeof(float) * NN * HID;
    float* xb        = (float*)ws;                ws += sizeof(float) * NN * HID;
    float* agg1      = (float*)ws;                ws += sizeof(float) * NN * HID;
    float* ha        = (float*)ws;                ws += sizeof(float) * NN * NCLS;
    float* hb        = (float*)ws;                ws += sizeof(float) * NN * NCLS;

    k_hist<<<GP, 256, 0, stream>>>(row, blockhist);
    k_scan_block<<<NBS, SCAN_CHUNK, 0, stream>>>(blockhist, scanExcl, bsum, NTOT);
    k_scan_tops<<<1, 64, 0, stream>>>(bsum, NBS);
    k_scan_add<<<(NTOT + 255) / 256, 256, 0, stream>>>(scanExcl, bsum, NTOT);
    k_partition<<<GP, 256, 0, stream>>>(row, col, ew, scanExcl, part);
    k_bucket_sort<<<NBKT, 256, 0, stream>>>(part, scanExcl, rowptr);
    k_dinv<<<(NN + 255) / 256, 256, 0, stream>>>(rowptr, part, dinv);
    k_proj1<<<(NN + 255) / 256, 256, 0, stream>>>(x, W1_0, W1_1, b1, xa, xb);
    k_gather1<<<(NN * 16 + 255) / 256, 256, 0, stream>>>(rowptr, part, dinv, xb, agg1);
    k_proj2<<<(NN + 255) / 256, 256, 0, stream>>>(xa, agg1, W2_0, W2_1, b2, ha, hb);
    k_gather2_lsm<<<(NN * 32 + 255) / 256, 256, 0, stream>>>(rowptr, part, dinv, ha, hb, out);
}

// Round 4
// 350.944 us; speedup vs baseline: 1.6819x; 1.1217x over previous
//
#include <hip/hip_runtime.h>
#include <hip/hip_bf16.h>

// DFAChebNet forward.
//  layer: x@W0 + (agg(x)-x)@W1 + b == x@(W0-W1) + agg(x@W1) + b   (project first)
//  aggregation: CSR pull-gather; CSR built by LDS-staged counting sort
//  (coalesced writes only -- scattered stores/atomics cost ~48B HBM each).
//  R4: bf16 feature tables (xb,hb), wave-per-node gathers with edge-parallel
//  lanes + unroll (8 lines in flight), pre-scaled edge weights w' = w*dinv[col]
//  so the inner loop is acc += w' * table[col] with dinv[row] factored out.

constexpr int NN   = 100000;
constexpr int NE   = 1600000;
constexpr int FIN  = 128;
constexpr int HID  = 16;
constexpr int NCLS = 32;

constexpr int RB    = 256;                         // rows per bucket
constexpr int NBKT  = (NN + RB - 1) / RB;          // 391
constexpr int EPB   = 8192;                        // edges per partition block
constexpr int GP    = (NE + EPB - 1) / EPB;        // 196
constexpr int NTOT  = NBKT * GP;                   // 76636
constexpr int SCAN_CHUNK = 512;
constexpr int NBS   = (NTOT + SCAN_CHUNK - 1) / SCAN_CHUNK;  // 150
constexpr int CAP   = 8192;                        // bucket edge cap (mean 4096)

static __device__ __forceinline__ unsigned short f2bf(float f) {
    union { float f; unsigned int u; } v; v.f = f;
    unsigned int r = v.u + 0x7fffu + ((v.u >> 16) & 1u);   // RNE
    return (unsigned short)(r >> 16);
}
static __device__ __forceinline__ float bf2f(unsigned short b) {
    union { unsigned int u; float f; } v; v.u = ((unsigned int)b) << 16;
    return v.f;
}

// ---- pass A: per-block bucket histogram (bucket-major output) ----
__global__ __launch_bounds__(256) void k_hist(const int* __restrict__ row,
                                              int* __restrict__ blockhist) {
    __shared__ int hist[NBKT];
    int tid = threadIdx.x;
    for (int i = tid; i < NBKT; i += 256) hist[i] = 0;
    __syncthreads();
    long ebase = (long)blockIdx.x * EPB;
#pragma unroll
    for (int i = 0; i < EPB / 256; i++) {
        long e = ebase + i * 256 + tid;
        if (e < NE) atomicAdd(&hist[row[e] >> 8], 1);
    }
    __syncthreads();
    for (int i = tid; i < NBKT; i += 256)
        blockhist[i * GP + blockIdx.x] = hist[i];
}

// ---- scan machinery ----
__global__ __launch_bounds__(SCAN_CHUNK) void k_scan_block(
    const int* __restrict__ in, int* __restrict__ outExcl,
    int* __restrict__ bsum, int n) {
    __shared__ int sh[SCAN_CHUNK];
    int tid = threadIdx.x;
    int i = blockIdx.x * SCAN_CHUNK + tid;
    int v = (i < n) ? in[i] : 0;
    sh[tid] = v;
    __syncthreads();
    for (int off = 1; off < SCAN_CHUNK; off <<= 1) {
        int t = (tid >= off) ? sh[tid - off] : 0;
        __syncthreads();
        sh[tid] += t;
        __syncthreads();
    }
    if (i < n) outExcl[i] = sh[tid] - v;
    if (tid == SCAN_CHUNK - 1) bsum[blockIdx.x] = sh[tid];
}

__global__ void k_scan_tops(int* __restrict__ bsum, int nb) {
    int lane = threadIdx.x;  // 64 threads
    int v[4], e[4];
    int s = 0;
#pragma unroll
    for (int t = 0; t < 4; t++) {
        int idx = lane * 4 + t;
        v[t] = (idx < nb) ? bsum[idx] : 0;
        e[t] = s;
        s += v[t];
    }
    int sc = s;
    for (int off = 1; off < 64; off <<= 1) {
        int up = __shfl_up(sc, off, 64);
        if (lane >= off) sc += up;
    }
    int excl = sc - s;
#pragma unroll
    for (int t = 0; t < 4; t++) {
        int idx = lane * 4 + t;
        if (idx < nb) bsum[idx] = excl + e[t];
    }
}

__global__ void k_scan_add(int* __restrict__ outExcl, const int* __restrict__ bsum, int n) {
    int i = blockIdx.x * blockDim.x + threadIdx.x;
    if (i < n) outExcl[i] += bsum[i >> 9];
}

// ---- pass B: LDS-staged partition by bucket, coalesced global writes ----
__global__ __launch_bounds__(256) void k_partition(
    const int* __restrict__ row, const int* __restrict__ col,
    const float* __restrict__ w, const int* __restrict__ scanExcl,
    int2* __restrict__ part) {
    __shared__ int2 stage[EPB];          // 64KB
    __shared__ int cnt[NBKT];
    __shared__ int lofs[NBKT];
    __shared__ int cursor[NBKT];
    __shared__ int gbase[NBKT];
    __shared__ int sa[512], sb[512];
    int tid = threadIdx.x;
    long ebase = (long)blockIdx.x * EPB;
    for (int i = tid; i < NBKT; i += 256) cnt[i] = 0;
    __syncthreads();
#pragma unroll
    for (int i = 0; i < EPB / 256; i++) {
        long e = ebase + i * 256 + tid;
        if (e < NE) atomicAdd(&cnt[row[e] >> 8], 1);
    }
    __syncthreads();
    for (int i = tid; i < 512; i += 256) sa[i] = (i < NBKT) ? cnt[i] : 0;
    __syncthreads();
    int* src = sa; int* dst = sb;
    for (int off = 1; off < 512; off <<= 1) {
        for (int i = tid; i < 512; i += 256)
            dst[i] = src[i] + ((i >= off) ? src[i - off] : 0);
        __syncthreads();
        int* t = src; src = dst; dst = t;
    }
    for (int i = tid; i < NBKT; i += 256) {
        int ex = src[i] - cnt[i];
        lofs[i] = ex;
        cursor[i] = ex;
        gbase[i] = scanExcl[i * GP + blockIdx.x];
    }
    __syncthreads();
#pragma unroll
    for (int i = 0; i < EPB / 256; i++) {
        long e = ebase + i * 256 + tid;
        if (e < NE) {
            int r = row[e];
            int b = r >> 8;
            int p = atomicAdd(&cursor[b], 1);
            int2 v;
            v.x = col[e] | ((r & 255) << 17);   // col<2^17, rowlow in bits 17..24
            v.y = __float_as_int(w[e]);
            stage[p] = v;
        }
    }
    __syncthreads();
    int total = (int)min((long)EPB, NE - ebase);
    for (int i = tid; i < total; i += 256) {
        int lo = 0, hi = NBKT - 1;
        while (lo < hi) {
            int mid = (lo + hi + 1) >> 1;
            if (lofs[mid] <= i) lo = mid; else hi = mid - 1;
        }
        part[gbase[lo] + (i - lofs[lo])] = stage[i];
    }
}

// ---- pass C: in-place per-bucket sort by row; emits rowptr AND dinv ----
__global__ __launch_bounds__(256) void k_bucket_sort(
    int2* __restrict__ part, const int* __restrict__ scanExcl,
    int* __restrict__ rowptr, float* __restrict__ dinv) {
    __shared__ int2 stage[CAP];          // 64KB
    __shared__ int hist[RB];
    __shared__ int cursor[RB];
    __shared__ int wtot[4];
    int b = blockIdx.x;
    int tid = threadIdx.x;
    int start = scanExcl[b * GP];
    int end = (b + 1 < NBKT) ? scanExcl[(b + 1) * GP] : NE;
    int count = end - start;
    hist[tid] = 0;
    __syncthreads();
    for (int i = tid; i < count; i += 256)
        atomicAdd(&hist[(part[start + i].x >> 17) & 255], 1);
    __syncthreads();
    int lane = tid & 63, wv = tid >> 6;
    int v = hist[tid];
    int sc = v;
#pragma unroll
    for (int off = 1; off < 64; off <<= 1) {
        int up = __shfl_up(sc, off, 64);
        if (lane >= off) sc += up;
    }
    if (lane == 63) wtot[wv] = sc;
    __syncthreads();
    int add = 0;
    for (int w2 = 0; w2 < wv; w2++) add += wtot[w2];
    int ex = sc + add - v;
    int node = b * RB + tid;
    if (node <= NN) rowptr[node] = start + ex;   // node==NN -> NE (last bucket)
    cursor[tid] = ex;
    __syncthreads();
    for (int i = tid; i < count; i += 256) {
        int2 p = part[start + i];
        int rl = (p.x >> 17) & 255;
        int pos = atomicAdd(&cursor[rl], 1);
        int2 c; c.x = p.x & 0x1FFFF; c.y = p.y;
        if (pos < CAP) stage[pos] = c;
    }
    __syncthreads();
    // per-row weight sums -> dinv (row tid local range = [ex, cursor[tid]))
    {
        int rend = cursor[tid];
        float d = 0.f;
        for (int i = ex; i < rend; i++) d += __int_as_float(stage[i].y);
        if (node < NN) dinv[node] = d > 0.f ? rsqrtf(d) : 0.f;
    }
    for (int i = tid; i < count; i += 256)
        if (i < CAP) part[start + i] = stage[i];
}

// part[j].w *= dinv[part[j].col]  (2 edges/thread, int4)
__global__ __launch_bounds__(256) void k_scalew(int2* __restrict__ part,
                                                const float* __restrict__ dinv) {
    long i = (long)blockIdx.x * 256 + threadIdx.x;
    if (i * 2 >= NE) return;
    int4* p4 = (int4*)part;
    int4 v = p4[i];
    v.y = __float_as_int(__int_as_float(v.y) * dinv[v.x]);
    v.w = __float_as_int(__int_as_float(v.w) * dinv[v.z]);
    p4[i] = v;
}

// xa = x@(W1_0-W1_1)+b1 (fp32) ; xb = x@W1_1 (bf16).  1 thread = 1 node.
__global__ __launch_bounds__(256) void k_proj1(
    const float* __restrict__ x, const float* __restrict__ W0,
    const float* __restrict__ W1, const float* __restrict__ b1,
    float* __restrict__ xa, unsigned short* __restrict__ xb16) {
    __shared__ float xs[256 * 33];
    int tid = threadIdx.x;
    long nbase = (long)blockIdx.x * 256;
    float accA[HID], accB[HID];
#pragma unroll
    for (int o = 0; o < HID; o++) { accA[o] = 0.f; accB[o] = 0.f; }
    const float4* xg = (const float4*)x;
    for (int c = 0; c < 4; c++) {
#pragma unroll
        for (int i = 0; i < 8; i++) {
            int j = i * 256 + tid;
            int node = j >> 3, w4 = j & 7;
            long gn = nbase + node;
            float4 v = make_float4(0.f, 0.f, 0.f, 0.f);
            if (gn < NN) v = xg[gn * 32 + c * 8 + w4];
            int base = node * 33 + w4 * 4;
            xs[base + 0] = v.x; xs[base + 1] = v.y;
            xs[base + 2] = v.z; xs[base + 3] = v.w;
        }
        __syncthreads();
#pragma unroll 4
        for (int kk = 0; kk < 32; kk++) {
            float xk = xs[tid * 33 + kk];
            int k = c * 32 + kk;
#pragma unroll
            for (int o = 0; o < HID; o++) accA[o] += xk * W0[k * HID + o];
#pragma unroll
            for (int o = 0; o < HID; o++) accB[o] += xk * W1[k * HID + o];
        }
        __syncthreads();
    }
    long n = nbase + tid;
    if (n >= NN) return;
    float4* xap = (float4*)(xa + n * HID);
#pragma unroll
    for (int q = 0; q < 4; q++) {
        float4 va;
        va.x = accA[4*q+0] - accB[4*q+0] + b1[4*q+0];
        va.y = accA[4*q+1] - accB[4*q+1] + b1[4*q+1];
        va.z = accA[4*q+2] - accB[4*q+2] + b1[4*q+2];
        va.w = accA[4*q+3] - accB[4*q+3] + b1[4*q+3];
        xap[q] = va;
    }
    unsigned int pk[8];
#pragma unroll
    for (int i = 0; i < 8; i++)
        pk[i] = (unsigned int)f2bf(accB[2*i]) | ((unsigned int)f2bf(accB[2*i+1]) << 16);
    uint4* xbp = (uint4*)(xb16 + n * HID);
    xbp[0] = make_uint4(pk[0], pk[1], pk[2], pk[3]);
    xbp[1] = make_uint4(pk[4], pk[5], pk[6], pk[7]);
}

// agg1[n,f] = dinv[n] * sum_j w'_j * xb[c_j,f].  1 wave = 1 node; 4 edges x 16 feats.
__global__ __launch_bounds__(256) void k_gather1(
    const int* __restrict__ rowptr, const int2* __restrict__ part,
    const float* __restrict__ dinv, const unsigned short* __restrict__ xb16,
    float* __restrict__ agg1) {
    long t = (long)blockIdx.x * 256 + threadIdx.x;
    int n = (int)(t >> 6);
    if (n >= NN) return;
    int lane = threadIdx.x & 63;
    int f = lane & 15, p = lane >> 4;     // p in 0..3
    int s = rowptr[n], e = rowptr[n + 1];
    float acc = 0.f;
    int j = s + p;
    while (j + 4 < e) {                    // j and j+4 both valid
        int2 e0 = part[j], e1 = part[j + 4];
        float v0 = bf2f(xb16[e0.x * HID + f]);
        float v1 = bf2f(xb16[e1.x * HID + f]);
        acc += __int_as_float(e0.y) * v0 + __int_as_float(e1.y) * v1;
        j += 8;
    }
    if (j < e) {
        int2 e0 = part[j];
        acc += __int_as_float(e0.y) * bf2f(xb16[e0.x * HID + f]);
    }
    acc += __shfl_xor(acc, 16);
    acc += __shfl_xor(acc, 32);
    if (p == 0) agg1[n * HID + f] = dinv[n] * acc;
}

// h = relu(xa+agg1); ha = h@(W2_0-W2_1)+b2 (fp32) ; hb = h@W2_1 (bf16).
__global__ __launch_bounds__(256) void k_proj2(
    const float* __restrict__ xa, const float* __restrict__ agg1,
    const float* __restrict__ W0, const float* __restrict__ W1,
    const float* __restrict__ b2,
    float* __restrict__ ha, unsigned short* __restrict__ hb16) {
    long n = (long)blockIdx.x * 256 + threadIdx.x;
    if (n >= NN) return;
    float h[HID];
    const float4* xap = (const float4*)(xa + n * HID);
    const float4* agp = (const float4*)(agg1 + n * HID);
#pragma unroll
    for (int q = 0; q < 4; q++) {
        float4 a = xap[q], g = agp[q];
        h[4*q+0] = fmaxf(a.x + g.x, 0.f);
        h[4*q+1] = fmaxf(a.y + g.y, 0.f);
        h[4*q+2] = fmaxf(a.z + g.z, 0.f);
        h[4*q+3] = fmaxf(a.w + g.w, 0.f);
    }
    float accA[NCLS], accB[NCLS];
#pragma unroll
    for (int o = 0; o < NCLS; o++) { accA[o] = 0.f; accB[o] = 0.f; }
#pragma unroll 2
    for (int k = 0; k < HID; k++) {
        float hk = h[k];
#pragma unroll
        for (int o = 0; o < NCLS; o++) accA[o] += hk * W0[k * NCLS + o];
#pragma unroll
        for (int o = 0; o < NCLS; o++) accB[o] += hk * W1[k * NCLS + o];
    }
    float4* hap = (float4*)(ha + n * NCLS);
#pragma unroll
    for (int q = 0; q < 8; q++) {
        float4 va;
        va.x = accA[4*q+0] - accB[4*q+0] + b2[4*q+0];
        va.y = accA[4*q+1] - accB[4*q+1] + b2[4*q+1];
        va.z = accA[4*q+2] - accB[4*q+2] + b2[4*q+2];
        va.w = accA[4*q+3] - accB[4*q+3] + b2[4*q+3];
        hap[q] = va;
    }
    uint4* hbp = (uint4*)(hb16 + n * NCLS);
#pragma unroll
    for (int q = 0; q < 4; q++) {
        unsigned int p0 = (unsigned int)f2bf(accB[8*q+0]) | ((unsigned int)f2bf(accB[8*q+1]) << 16);
        unsigned int p1 = (unsigned int)f2bf(accB[8*q+2]) | ((unsigned int)f2bf(accB[8*q+3]) << 16);
        unsigned int p2 = (unsigned int)f2bf(accB[8*q+4]) | ((unsigned int)f2bf(accB[8*q+5]) << 16);
        unsigned int p3 = (unsigned int)f2bf(accB[8*q+6]) | ((unsigned int)f2bf(accB[8*q+7]) << 16);
        hbp[q] = make_uint4(p0, p1, p2, p3);
    }
}

// out[n,:] = log_softmax(ha[n,:] + dinv[n]*sum_j w'_j*hb[c_j,:]).
// 1 wave = 1 node; 2 edges x 32 classes, unroll 4 (8 lines in flight).
__global__ __launch_bounds__(256) void k_gather2_lsm(
    const int* __restrict__ rowptr, const int2* __restrict__ part,
    const float* __restrict__ dinv, const float* __restrict__ ha,
    const unsigned short* __restrict__ hb16, float* __restrict__ out) {
    long t = (long)blockIdx.x * 256 + threadIdx.x;
    int n = (int)(t >> 6);
    if (n >= NN) return;
    int lane = threadIdx.x & 63;
    int o = lane & 31, p = lane >> 5;     // p in 0..1
    int s = rowptr[n], e = rowptr[n + 1];
    float acc = 0.f;
    int j = s + p;
    while (j + 6 < e) {                    // j, j+2, j+4, j+6 all valid
        int2 e0 = part[j], e1 = part[j + 2], e2 = part[j + 4], e3 = part[j + 6];
        float v0 = bf2f(hb16[e0.x * NCLS + o]);
        float v1 = bf2f(hb16[e1.x * NCLS + o]);
        float v2 = bf2f(hb16[e2.x * NCLS + o]);
        float v3 = bf2f(hb16[e3.x * NCLS + o]);
        acc += __int_as_float(e0.y) * v0 + __int_as_float(e1.y) * v1
             + __int_as_float(e2.y) * v2 + __int_as_float(e3.y) * v3;
        j += 8;
    }
    while (j < e) {
        int2 ed = part[j];
        acc += __int_as_float(ed.y) * bf2f(hb16[ed.x * NCLS + o]);
        j += 2;
    }
    acc += __shfl_xor(acc, 32);           // combine the two edge-parity halves
    float vo = dinv[n] * acc + ha[n * NCLS + o];
    float m = vo;
    for (int sh = 16; sh > 0; sh >>= 1) m = fmaxf(m, __shfl_xor(m, sh, 32));
    float ex2 = __expf(vo - m);
    float sum = ex2;
    for (int sh = 16; sh > 0; sh >>= 1) sum += __shfl_xor(sum, sh, 32);
    if (p == 0) out[n * NCLS + o] = (vo - m) - logf(sum);
}

extern "C" void kernel_launch(void* const* d_in, const int* in_sizes, int n_in,
                              void* d_out, int out_size, void* d_ws, size_t ws_size,
                              hipStream_t stream) {
    const float* x    = (const float*)d_in[0];
    const int*   ei   = (const int*)d_in[1];
    const float* ew   = (const float*)d_in[2];
    const float* W1_0 = (const float*)d_in[3];
    const float* W1_1 = (const float*)d_in[4];
    const float* b1   = (const float*)d_in[5];
    const float* W2_0 = (const float*)d_in[6];
    const float* W2_1 = (const float*)d_in[7];
    const float* b2   = (const float*)d_in[8];
    float* out = (float*)d_out;

    const int* row = ei;
    const int* col = ei + NE;

    char* ws = (char*)d_ws;
    int2*  part      = (int2*)ws;                 ws += sizeof(int2) * NE;
    int*   blockhist = (int*)ws;                  ws += sizeof(int) * NTOT;
    int*   scanExcl  = (int*)ws;                  ws += sizeof(int) * NTOT;
    int*   bsum      = (int*)ws;                  ws += sizeof(int) * 256;
    int*   rowptr    = (int*)ws;                  ws += sizeof(int) * (NN + 4);
    float* dinv      = (float*)ws;                ws += sizeof(float) * NN;
    float* xa        = (float*)ws;                ws += sizeof(float) * NN * HID;
    unsigned short* xb16 = (unsigned short*)ws;   ws += sizeof(short) * NN * HID;
    float* agg1      = (float*)ws;                ws += sizeof(float) * NN * HID;
    float* ha        = (float*)ws;                ws += sizeof(float) * NN * NCLS;
    unsigned short* hb16 = (unsigned short*)ws;   ws += sizeof(short) * NN * NCLS;

    k_hist<<<GP, 256, 0, stream>>>(row, blockhist);
    k_scan_block<<<NBS, SCAN_CHUNK, 0, stream>>>(blockhist, scanExcl, bsum, NTOT);
    k_scan_tops<<<1, 64, 0, stream>>>(bsum, NBS);
    k_scan_add<<<(NTOT + 255) / 256, 256, 0, stream>>>(scanExcl, bsum, NTOT);
    k_partition<<<GP, 256, 0, stream>>>(row, col, ew, scanExcl, part);
    k_bucket_sort<<<NBKT, 256, 0, stream>>>(part, scanExcl, rowptr, dinv);
    k_scalew<<<(NE / 2 + 255) / 256, 256, 0, stream>>>(part, dinv);
    k_proj1<<<(NN + 255) / 256, 256, 0, stream>>>(x, W1_0, W1_1, b1, xa, xb16);
    {
        long th = (long)NN * 64;
        k_gather1<<<(int)((th + 255) / 256), 256, 0, stream>>>(rowptr, part, dinv, xb16, agg1);
    }
    k_proj2<<<(NN + 255) / 256, 256, 0, stream>>>(xa, agg1, W2_0, W2_1, b2, ha, hb16);
    {
        long th = (long)NN * 64;
        k_gather2_lsm<<<(int)((th + 255) / 256), 256, 0, stream>>>(rowptr, part, dinv, ha, hb16, out);
    }
}

// Round 5
// 309.220 us; speedup vs baseline: 1.9089x; 1.1349x over previous
//
#include <hip/hip_runtime.h>
#include <hip/hip_bf16.h>

// DFAChebNet forward.
//  layer: x@W0 + (agg(x)-x)@W1 + b == x@(W0-W1) + agg(x@W1) + b   (project first)
//  aggregation: CSR pull-gather; CSR built by LDS-staged counting sort
//  (coalesced writes only -- scattered stores/atomics cost ~48B HBM each).
//  R5: partition uses register-held edges + bucket-id side array (no binary
//  search), EPB=4096 for 2x block parallelism; hb table in fp8 e4m3 so the
//  layer-2 gather table (3.2MB) fits a single XCD L2 (4MB).

constexpr int NN   = 100000;
constexpr int NE   = 1600000;
constexpr int FIN  = 128;
constexpr int HID  = 16;
constexpr int NCLS = 32;

constexpr int RB    = 256;                         // rows per bucket
constexpr int NBKT  = (NN + RB - 1) / RB;          // 391
constexpr int EPB   = 4096;                        // edges per partition block
constexpr int EPT   = EPB / 256;                   // 16 edges per thread
constexpr int GP    = (NE + EPB - 1) / EPB;        // 391
constexpr int NTOT  = NBKT * GP;                   // 152881
constexpr int SCAN_CHUNK = 512;
constexpr int NBS   = (NTOT + SCAN_CHUNK - 1) / SCAN_CHUNK;  // 299
constexpr int CAP   = 8192;                        // bucket edge cap (mean 4096)

static __device__ __forceinline__ unsigned short f2bf(float f) {
    union { float f; unsigned int u; } v; v.f = f;
    unsigned int r = v.u + 0x7fffu + ((v.u >> 16) & 1u);   // RNE
    return (unsigned short)(r >> 16);
}
static __device__ __forceinline__ float bf2f(unsigned short b) {
    union { unsigned int u; float f; } v; v.u = ((unsigned int)b) << 16;
    return v.f;
}
// fp8 e4m3fn encode (RNE, subnormals flushed to 0, clamp at 448)
static __device__ __forceinline__ unsigned int f2e4m3(float f) {
    union { float f; unsigned int u; } v; v.f = f;
    unsigned int s = (v.u >> 24) & 0x80u;
    unsigned int au = v.u & 0x7fffffffu;
    if (au > 0x43E00000u) au = 0x43E00000u;        // clamp to 448
    au += 0x7ffffu + ((au >> 20) & 1u);            // RNE into 3-bit mantissa
    int e4 = (int)(au >> 23) - 120;                // 127-7
    unsigned int m = (au >> 20) & 7u;
    unsigned int byte = (e4 <= 0) ? 0u : (((unsigned int)e4 << 3) | m);
    return s | byte;
}
// decode: value = as_float(bits<<20 into fp32) * 2^120; fold 2^120 into weight
static __device__ __forceinline__ float e4m3_mul(unsigned int b, float wscaled) {
    unsigned int u = ((b & 0x80u) << 24) | ((b & 0x7fu) << 20);
    return __int_as_float((int)u) * wscaled;
}

// ---- pass A: per-block bucket histogram (bucket-major output) ----
__global__ __launch_bounds__(256) void k_hist(const int* __restrict__ row,
                                              int* __restrict__ blockhist) {
    __shared__ int hist[NBKT];
    int tid = threadIdx.x;
    for (int i = tid; i < NBKT; i += 256) hist[i] = 0;
    __syncthreads();
    long ebase = (long)blockIdx.x * EPB;
#pragma unroll
    for (int i = 0; i < EPT; i++) {
        long e = ebase + i * 256 + tid;
        if (e < NE) atomicAdd(&hist[row[e] >> 8], 1);
    }
    __syncthreads();
    for (int i = tid; i < NBKT; i += 256)
        blockhist[i * GP + blockIdx.x] = hist[i];
}

// ---- scan machinery ----
__global__ __launch_bounds__(SCAN_CHUNK) void k_scan_block(
    const int* __restrict__ in, int* __restrict__ outExcl,
    int* __restrict__ bsum, int n) {
    __shared__ int sh[SCAN_CHUNK];
    int tid = threadIdx.x;
    int i = blockIdx.x * SCAN_CHUNK + tid;
    int v = (i < n) ? in[i] : 0;
    sh[tid] = v;
    __syncthreads();
    for (int off = 1; off < SCAN_CHUNK; off <<= 1) {
        int t = (tid >= off) ? sh[tid - off] : 0;
        __syncthreads();
        sh[tid] += t;
        __syncthreads();
    }
    if (i < n) outExcl[i] = sh[tid] - v;
    if (tid == SCAN_CHUNK - 1) bsum[blockIdx.x] = sh[tid];
}

// exclusive scan of bsum (<= 512 entries), single wave, 8 per lane
__global__ void k_scan_tops(int* __restrict__ bsum, int nb) {
    int lane = threadIdx.x;  // 64 threads
    int v[8], e[8];
    int s = 0;
#pragma unroll
    for (int t = 0; t < 8; t++) {
        int idx = lane * 8 + t;
        v[t] = (idx < nb) ? bsum[idx] : 0;
        e[t] = s;
        s += v[t];
    }
    int sc = s;
    for (int off = 1; off < 64; off <<= 1) {
        int up = __shfl_up(sc, off, 64);
        if (lane >= off) sc += up;
    }
    int excl = sc - s;
#pragma unroll
    for (int t = 0; t < 8; t++) {
        int idx = lane * 8 + t;
        if (idx < nb) bsum[idx] = excl + e[t];
    }
}

__global__ void k_scan_add(int* __restrict__ outExcl, const int* __restrict__ bsum, int n) {
    int i = blockIdx.x * blockDim.x + threadIdx.x;
    if (i < n) outExcl[i] += bsum[i >> 9];
}

// ---- pass B: LDS-staged partition by bucket, coalesced global writes ----
__global__ __launch_bounds__(256) void k_partition(
    const int* __restrict__ row, const int* __restrict__ col,
    const float* __restrict__ w, const int* __restrict__ scanExcl,
    int2* __restrict__ part) {
    __shared__ int2 stage[EPB];              // 32KB
    __shared__ unsigned short sbkt[EPB];     // 8KB: bucket id of each staged slot
    __shared__ int cnt[NBKT];
    __shared__ int lofs[NBKT];
    __shared__ int cursor[NBKT];
    __shared__ int gbase[NBKT];
    __shared__ int sa[512], sb[512];
    int tid = threadIdx.x;
    long ebase = (long)blockIdx.x * EPB;
    // load this thread's edges into registers (coalesced)
    int rr[EPT]; int cc[EPT]; float wv[EPT];
#pragma unroll
    for (int i = 0; i < EPT; i++) {
        long e = ebase + i * 256 + tid;
        if (e < NE) { rr[i] = row[e]; cc[i] = col[e]; wv[i] = w[e]; }
        else rr[i] = -1;
    }
    for (int i = tid; i < NBKT; i += 256) cnt[i] = 0;
    __syncthreads();
#pragma unroll
    for (int i = 0; i < EPT; i++)
        if (rr[i] >= 0) atomicAdd(&cnt[rr[i] >> 8], 1);
    __syncthreads();
    for (int i = tid; i < 512; i += 256) sa[i] = (i < NBKT) ? cnt[i] : 0;
    __syncthreads();
    int* src = sa; int* dst = sb;
    for (int off = 1; off < 512; off <<= 1) {
        for (int i = tid; i < 512; i += 256)
            dst[i] = src[i] + ((i >= off) ? src[i - off] : 0);
        __syncthreads();
        int* t = src; src = dst; dst = t;
    }
    for (int i = tid; i < NBKT; i += 256) {
        int ex = src[i] - cnt[i];
        lofs[i] = ex;
        cursor[i] = ex;
        gbase[i] = scanExcl[i * GP + blockIdx.x];
    }
    __syncthreads();
#pragma unroll
    for (int i = 0; i < EPT; i++) {
        if (rr[i] >= 0) {
            int b = rr[i] >> 8;
            int p = atomicAdd(&cursor[b], 1);
            int2 v;
            v.x = cc[i] | ((rr[i] & 255) << 17);  // col<2^17, rowlow bits 17..24
            v.y = __float_as_int(wv[i]);
            stage[p] = v;
            sbkt[p] = (unsigned short)b;
        }
    }
    __syncthreads();
    int total = (int)min((long)EPB, NE - ebase);
    for (int i = tid; i < total; i += 256) {
        int b = sbkt[i];
        part[gbase[b] + (i - lofs[b])] = stage[i];
    }
}

// ---- pass C: in-place per-bucket sort by row; emits rowptr AND dinv ----
__global__ __launch_bounds__(256) void k_bucket_sort(
    int2* __restrict__ part, const int* __restrict__ scanExcl,
    int* __restrict__ rowptr, float* __restrict__ dinv) {
    __shared__ int2 stage[CAP];          // 64KB
    __shared__ int hist[RB];
    __shared__ int cursor[RB];
    __shared__ int wtot[4];
    int b = blockIdx.x;
    int tid = threadIdx.x;
    int start = scanExcl[b * GP];
    int end = (b + 1 < NBKT) ? scanExcl[(b + 1) * GP] : NE;
    int count = end - start;
    hist[tid] = 0;
    __syncthreads();
    for (int i = tid; i < count; i += 256)
        atomicAdd(&hist[(part[start + i].x >> 17) & 255], 1);
    __syncthreads();
    int lane = tid & 63, wv = tid >> 6;
    int v = hist[tid];
    int sc = v;
#pragma unroll
    for (int off = 1; off < 64; off <<= 1) {
        int up = __shfl_up(sc, off, 64);
        if (lane >= off) sc += up;
    }
    if (lane == 63) wtot[wv] = sc;
    __syncthreads();
    int add = 0;
    for (int w2 = 0; w2 < wv; w2++) add += wtot[w2];
    int ex = sc + add - v;
    int node = b * RB + tid;
    if (node <= NN) rowptr[node] = start + ex;   // node==NN -> NE (last bucket)
    cursor[tid] = ex;
    __syncthreads();
    for (int i = tid; i < count; i += 256) {
        int2 p = part[start + i];
        int rl = (p.x >> 17) & 255;
        int pos = atomicAdd(&cursor[rl], 1);
        int2 c; c.x = p.x & 0x1FFFF; c.y = p.y;
        if (pos < CAP) stage[pos] = c;
    }
    __syncthreads();
    {
        int rend = cursor[tid];
        float d = 0.f;
        for (int i = ex; i < rend; i++) d += __int_as_float(stage[i].y);
        if (node < NN) dinv[node] = d > 0.f ? rsqrtf(d) : 0.f;
    }
    for (int i = tid; i < count; i += 256)
        if (i < CAP) part[start + i] = stage[i];
}

// part[j].w *= dinv[part[j].col]  (2 edges/thread, int4)
__global__ __launch_bounds__(256) void k_scalew(int2* __restrict__ part,
                                                const float* __restrict__ dinv) {
    long i = (long)blockIdx.x * 256 + threadIdx.x;
    if (i * 2 >= NE) return;
    int4* p4 = (int4*)part;
    int4 v = p4[i];
    v.y = __float_as_int(__int_as_float(v.y) * dinv[v.x]);
    v.w = __float_as_int(__int_as_float(v.w) * dinv[v.z]);
    p4[i] = v;
}

// xa = x@(W1_0-W1_1)+b1 (fp32) ; xb = x@W1_1 (bf16).  1 thread = 1 node.
__global__ __launch_bounds__(256) void k_proj1(
    const float* __restrict__ x, const float* __restrict__ W0,
    const float* __restrict__ W1, const float* __restrict__ b1,
    float* __restrict__ xa, unsigned short* __restrict__ xb16) {
    __shared__ float xs[256 * 33];
    int tid = threadIdx.x;
    long nbase = (long)blockIdx.x * 256;
    float accA[HID], accB[HID];
#pragma unroll
    for (int o = 0; o < HID; o++) { accA[o] = 0.f; accB[o] = 0.f; }
    const float4* xg = (const float4*)x;
    for (int c = 0; c < 4; c++) {
#pragma unroll
        for (int i = 0; i < 8; i++) {
            int j = i * 256 + tid;
            int node = j >> 3, w4 = j & 7;
            long gn = nbase + node;
            float4 v = make_float4(0.f, 0.f, 0.f, 0.f);
            if (gn < NN) v = xg[gn * 32 + c * 8 + w4];
            int base = node * 33 + w4 * 4;
            xs[base + 0] = v.x; xs[base + 1] = v.y;
            xs[base + 2] = v.z; xs[base + 3] = v.w;
        }
        __syncthreads();
#pragma unroll 4
        for (int kk = 0; kk < 32; kk++) {
            float xk = xs[tid * 33 + kk];
            int k = c * 32 + kk;
#pragma unroll
            for (int o = 0; o < HID; o++) accA[o] += xk * W0[k * HID + o];
#pragma unroll
            for (int o = 0; o < HID; o++) accB[o] += xk * W1[k * HID + o];
        }
        __syncthreads();
    }
    long n = nbase + tid;
    if (n >= NN) return;
    float4* xap = (float4*)(xa + n * HID);
#pragma unroll
    for (int q = 0; q < 4; q++) {
        float4 va;
        va.x = accA[4*q+0] - accB[4*q+0] + b1[4*q+0];
        va.y = accA[4*q+1] - accB[4*q+1] + b1[4*q+1];
        va.z = accA[4*q+2] - accB[4*q+2] + b1[4*q+2];
        va.w = accA[4*q+3] - accB[4*q+3] + b1[4*q+3];
        xap[q] = va;
    }
    unsigned int pk[8];
#pragma unroll
    for (int i = 0; i < 8; i++)
        pk[i] = (unsigned int)f2bf(accB[2*i]) | ((unsigned int)f2bf(accB[2*i+1]) << 16);
    uint4* xbp = (uint4*)(xb16 + n * HID);
    xbp[0] = make_uint4(pk[0], pk[1], pk[2], pk[3]);
    xbp[1] = make_uint4(pk[4], pk[5], pk[6], pk[7]);
}

// agg1[n,f] = dinv[n] * sum_j w'_j * xb[c_j,f].  1 wave = 1 node; 4 edges x 16 feats.
__global__ __launch_bounds__(256) void k_gather1(
    const int* __restrict__ rowptr, const int2* __restrict__ part,
    const float* __restrict__ dinv, const unsigned short* __restrict__ xb16,
    float* __restrict__ agg1) {
    long t = (long)blockIdx.x * 256 + threadIdx.x;
    int n = (int)(t >> 6);
    if (n >= NN) return;
    int lane = threadIdx.x & 63;
    int f = lane & 15, p = lane >> 4;     // p in 0..3
    int s = rowptr[n], e = rowptr[n + 1];
    float acc = 0.f;
    int j = s + p;
    while (j + 4 < e) {
        int2 e0 = part[j], e1 = part[j + 4];
        float v0 = bf2f(xb16[e0.x * HID + f]);
        float v1 = bf2f(xb16[e1.x * HID + f]);
        acc += __int_as_float(e0.y) * v0 + __int_as_float(e1.y) * v1;
        j += 8;
    }
    if (j < e) {
        int2 e0 = part[j];
        acc += __int_as_float(e0.y) * bf2f(xb16[e0.x * HID + f]);
    }
    acc += __shfl_xor(acc, 16);
    acc += __shfl_xor(acc, 32);
    if (p == 0) agg1[n * HID + f] = dinv[n] * acc;
}

// h = relu(xa+agg1); ha = h@(W2_0-W2_1)+b2 (fp32) ; hb = h@W2_1 (fp8 e4m3).
__global__ __launch_bounds__(256) void k_proj2(
    const float* __restrict__ xa, const float* __restrict__ agg1,
    const float* __restrict__ W0, const float* __restrict__ W1,
    const float* __restrict__ b2,
    float* __restrict__ ha, unsigned char* __restrict__ hb8) {
    long n = (long)blockIdx.x * 256 + threadIdx.x;
    if (n >= NN) return;
    float h[HID];
    const float4* xap = (const float4*)(xa + n * HID);
    const float4* agp = (const float4*)(agg1 + n * HID);
#pragma unroll
    for (int q = 0; q < 4; q++) {
        float4 a = xap[q], g = agp[q];
        h[4*q+0] = fmaxf(a.x + g.x, 0.f);
        h[4*q+1] = fmaxf(a.y + g.y, 0.f);
        h[4*q+2] = fmaxf(a.z + g.z, 0.f);
        h[4*q+3] = fmaxf(a.w + g.w, 0.f);
    }
    float accA[NCLS], accB[NCLS];
#pragma unroll
    for (int o = 0; o < NCLS; o++) { accA[o] = 0.f; accB[o] = 0.f; }
#pragma unroll 2
    for (int k = 0; k < HID; k++) {
        float hk = h[k];
#pragma unroll
        for (int o = 0; o < NCLS; o++) accA[o] += hk * W0[k * NCLS + o];
#pragma unroll
        for (int o = 0; o < NCLS; o++) accB[o] += hk * W1[k * NCLS + o];
    }
    float4* hap = (float4*)(ha + n * NCLS);
#pragma unroll
    for (int q = 0; q < 8; q++) {
        float4 va;
        va.x = accA[4*q+0] - accB[4*q+0] + b2[4*q+0];
        va.y = accA[4*q+1] - accB[4*q+1] + b2[4*q+1];
        va.z = accA[4*q+2] - accB[4*q+2] + b2[4*q+2];
        va.w = accA[4*q+3] - accB[4*q+3] + b2[4*q+3];
        hap[q] = va;
    }
    unsigned int pk[8];
#pragma unroll
    for (int q = 0; q < 8; q++)
        pk[q] = f2e4m3(accB[4*q+0]) | (f2e4m3(accB[4*q+1]) << 8)
              | (f2e4m3(accB[4*q+2]) << 16) | (f2e4m3(accB[4*q+3]) << 24);
    uint4* hbp = (uint4*)(hb8 + n * NCLS);
    hbp[0] = make_uint4(pk[0], pk[1], pk[2], pk[3]);
    hbp[1] = make_uint4(pk[4], pk[5], pk[6], pk[7]);
}

// out[n,:] = log_softmax(ha[n,:] + dinv[n]*sum_j w'_j*hb[c_j,:]).
// 1 wave = 1 node; 2 edges x 32 classes, unroll 4 (8 lines in flight).
__global__ __launch_bounds__(256) void k_gather2_lsm(
    const int* __restrict__ rowptr, const int2* __restrict__ part,
    const float* __restrict__ dinv, const float* __restrict__ ha,
    const unsigned char* __restrict__ hb8, float* __restrict__ out) {
    long t = (long)blockIdx.x * 256 + threadIdx.x;
    int n = (int)(t >> 6);
    if (n >= NN) return;
    int lane = threadIdx.x & 63;
    int o = lane & 31, p = lane >> 5;     // p in 0..1
    int s = rowptr[n], e = rowptr[n + 1];
    float acc = 0.f;
    int j = s + p;
    while (j + 6 < e) {
        int2 e0 = part[j], e1 = part[j + 2], e2 = part[j + 4], e3 = part[j + 6];
        unsigned int b0 = hb8[e0.x * NCLS + o];
        unsigned int b1 = hb8[e1.x * NCLS + o];
        unsigned int b2 = hb8[e2.x * NCLS + o];
        unsigned int b3 = hb8[e3.x * NCLS + o];
        acc += e4m3_mul(b0, __int_as_float(e0.y) * 0x1p120f)
             + e4m3_mul(b1, __int_as_float(e1.y) * 0x1p120f)
             + e4m3_mul(b2, __int_as_float(e2.y) * 0x1p120f)
             + e4m3_mul(b3, __int_as_float(e3.y) * 0x1p120f);
        j += 8;
    }
    while (j < e) {
        int2 ed = part[j];
        acc += e4m3_mul(hb8[ed.x * NCLS + o], __int_as_float(ed.y) * 0x1p120f);
        j += 2;
    }
    acc += __shfl_xor(acc, 32);           // combine the two edge-parity halves
    float vo = dinv[n] * acc + ha[n * NCLS + o];
    float m = vo;
    for (int sh = 16; sh > 0; sh >>= 1) m = fmaxf(m, __shfl_xor(m, sh, 32));
    float ex2 = __expf(vo - m);
    float sum = ex2;
    for (int sh = 16; sh > 0; sh >>= 1) sum += __shfl_xor(sum, sh, 32);
    if (p == 0) out[n * NCLS + o] = (vo - m) - logf(sum);
}

extern "C" void kernel_launch(void* const* d_in, const int* in_sizes, int n_in,
                              void* d_out, int out_size, void* d_ws, size_t ws_size,
                              hipStream_t stream) {
    const float* x    = (const float*)d_in[0];
    const int*   ei   = (const int*)d_in[1];
    const float* ew   = (const float*)d_in[2];
    const float* W1_0 = (const float*)d_in[3];
    const float* W1_1 = (const float*)d_in[4];
    const float* b1   = (const float*)d_in[5];
    const float* W2_0 = (const float*)d_in[6];
    const float* W2_1 = (const float*)d_in[7];
    const float* b2   = (const float*)d_in[8];
    float* out = (float*)d_out;

    const int* row = ei;
    const int* col = ei + NE;

    char* ws = (char*)d_ws;
    int2*  part      = (int2*)ws;                 ws += sizeof(int2) * NE;
    int*   blockhist = (int*)ws;                  ws += sizeof(int) * NTOT;
    int*   scanExcl  = (int*)ws;                  ws += sizeof(int) * NTOT;
    int*   bsum      = (int*)ws;                  ws += sizeof(int) * 512;
    int*   rowptr    = (int*)ws;                  ws += sizeof(int) * (NN + 4);
    float* dinv      = (float*)ws;                ws += sizeof(float) * NN;
    float* xa        = (float*)ws;                ws += sizeof(float) * NN * HID;
    unsigned short* xb16 = (unsigned short*)ws;   ws += sizeof(short) * NN * HID;
    float* agg1      = (float*)ws;                ws += sizeof(float) * NN * HID;
    float* ha        = (float*)ws;                ws += sizeof(float) * NN * NCLS;
    unsigned char* hb8 = (unsigned char*)ws;      ws += sizeof(char) * NN * NCLS;

    k_hist<<<GP, 256, 0, stream>>>(row, blockhist);
    k_scan_block<<<NBS, SCAN_CHUNK, 0, stream>>>(blockhist, scanExcl, bsum, NTOT);
    k_scan_tops<<<1, 64, 0, stream>>>(bsum, NBS);
    k_scan_add<<<(NTOT + 255) / 256, 256, 0, stream>>>(scanExcl, bsum, NTOT);
    k_partition<<<GP, 256, 0, stream>>>(row, col, ew, scanExcl, part);
    k_bucket_sort<<<NBKT, 256, 0, stream>>>(part, scanExcl, rowptr, dinv);
    k_scalew<<<(NE / 2 + 255) / 256, 256, 0, stream>>>(part, dinv);
    k_proj1<<<(NN + 255) / 256, 256, 0, stream>>>(x, W1_0, W1_1, b1, xa, xb16);
    {
        long th = (long)NN * 64;
        k_gather1<<<(int)((th + 255) / 256), 256, 0, stream>>>(rowptr, part, dinv, xb16, agg1);
    }
    k_proj2<<<(NN + 255) / 256, 256, 0, stream>>>(xa, agg1, W2_0, W2_1, b2, ha, hb8);
    {
        long th = (long)NN * 64;
        k_gather2_lsm<<<(int)((th + 255) / 256), 256, 0, stream>>>(rowptr, part, dinv, ha, hb8, out);
    }
}

// Round 6
// 288.183 us; speedup vs baseline: 2.0482x; 1.0730x over previous
//
#include <hip/hip_runtime.h>
#include <hip/hip_bf16.h>

// DFAChebNet forward.
//  layer: x@W0 + (agg(x)-x)@W1 + b == x@(W0-W1) + agg(x@W1) + b   (project first)
//  aggregation: CSR pull-gather; CSR built by LDS-staged counting sort.
//  R6: both gather tables in fp8 e4m3fn; decode via v_cvt_pk_f32_fp8 (1 inst
//  per 2 values); lane = (edge parity, feature pair) so each lane does a
//  ushort load + cvt_pk + 2 fma per edge. 8 random lines in flight per wave.

constexpr int NN   = 100000;
constexpr int NE   = 1600000;
constexpr int FIN  = 128;
constexpr int HID  = 16;
constexpr int NCLS = 32;

constexpr int RB    = 256;                         // rows per bucket
constexpr int NBKT  = (NN + RB - 1) / RB;          // 391
constexpr int EPB   = 4096;                        // edges per partition block
constexpr int EPT   = EPB / 256;                   // 16 edges per thread
constexpr int GP    = (NE + EPB - 1) / EPB;        // 391
constexpr int NTOT  = NBKT * GP;                   // 152881
constexpr int SCAN_CHUNK = 512;
constexpr int NBS   = (NTOT + SCAN_CHUNK - 1) / SCAN_CHUNK;  // 299
constexpr int CAP   = 8192;                        // bucket edge cap (mean 4096)

typedef float f32x2 __attribute__((ext_vector_type(2)));

#if defined(__has_builtin)
#if __has_builtin(__builtin_amdgcn_cvt_pk_f32_fp8)
#define HAVE_CVT_FP8 1
#endif
#endif

// fp8 e4m3fn encode (RNE, subnormals flushed to 0, clamp at 448)
static __device__ __forceinline__ unsigned int f2e4m3(float f) {
    union { float f; unsigned int u; } v; v.f = f;
    unsigned int s = (v.u >> 24) & 0x80u;
    unsigned int au = v.u & 0x7fffffffu;
    if (au > 0x43E00000u) au = 0x43E00000u;        // clamp to 448
    au += 0x7ffffu + ((au >> 20) & 1u);            // RNE into 3-bit mantissa
    int e4 = (int)(au >> 23) - 120;                // 127-7
    unsigned int m = (au >> 20) & 7u;
    unsigned int byte = (e4 <= 0) ? 0u : (((unsigned int)e4 << 3) | m);
    return s | byte;
}
// decode 2 packed fp8 (low 16 bits) -> 2 floats
static __device__ __forceinline__ f32x2 fp8x2_to_f32(unsigned int v) {
#ifdef HAVE_CVT_FP8
    return __builtin_amdgcn_cvt_pk_f32_fp8((int)v, false);
#else
    unsigned int b0 = v & 0xffu, b1 = (v >> 8) & 0xffu;
    f32x2 r;
    r.x = __int_as_float((int)(((b0 & 0x80u) << 24) | ((b0 & 0x7fu) << 20))) * 0x1p120f;
    r.y = __int_as_float((int)(((b1 & 0x80u) << 24) | ((b1 & 0x7fu) << 20))) * 0x1p120f;
    return r;
#endif
}

// ---- pass A: per-block bucket histogram (bucket-major output) ----
__global__ __launch_bounds__(256) void k_hist(const int* __restrict__ row,
                                              int* __restrict__ blockhist) {
    __shared__ int hist[NBKT];
    int tid = threadIdx.x;
    for (int i = tid; i < NBKT; i += 256) hist[i] = 0;
    __syncthreads();
    long ebase = (long)blockIdx.x * EPB;
#pragma unroll
    for (int i = 0; i < EPT; i++) {
        long e = ebase + i * 256 + tid;
        if (e < NE) atomicAdd(&hist[row[e] >> 8], 1);
    }
    __syncthreads();
    for (int i = tid; i < NBKT; i += 256)
        blockhist[i * GP + blockIdx.x] = hist[i];
}

// ---- scan machinery ----
__global__ __launch_bounds__(SCAN_CHUNK) void k_scan_block(
    const int* __restrict__ in, int* __restrict__ outExcl,
    int* __restrict__ bsum, int n) {
    __shared__ int sh[SCAN_CHUNK];
    int tid = threadIdx.x;
    int i = blockIdx.x * SCAN_CHUNK + tid;
    int v = (i < n) ? in[i] : 0;
    sh[tid] = v;
    __syncthreads();
    for (int off = 1; off < SCAN_CHUNK; off <<= 1) {
        int t = (tid >= off) ? sh[tid - off] : 0;
        __syncthreads();
        sh[tid] += t;
        __syncthreads();
    }
    if (i < n) outExcl[i] = sh[tid] - v;
    if (tid == SCAN_CHUNK - 1) bsum[blockIdx.x] = sh[tid];
}

// exclusive scan of bsum (<= 512 entries), single wave, 8 per lane
__global__ void k_scan_tops(int* __restrict__ bsum, int nb) {
    int lane = threadIdx.x;  // 64 threads
    int v[8], e[8];
    int s = 0;
#pragma unroll
    for (int t = 0; t < 8; t++) {
        int idx = lane * 8 + t;
        v[t] = (idx < nb) ? bsum[idx] : 0;
        e[t] = s;
        s += v[t];
    }
    int sc = s;
    for (int off = 1; off < 64; off <<= 1) {
        int up = __shfl_up(sc, off, 64);
        if (lane >= off) sc += up;
    }
    int excl = sc - s;
#pragma unroll
    for (int t = 0; t < 8; t++) {
        int idx = lane * 8 + t;
        if (idx < nb) bsum[idx] = excl + e[t];
    }
}

__global__ void k_scan_add(int* __restrict__ outExcl, const int* __restrict__ bsum, int n) {
    int i = blockIdx.x * blockDim.x + threadIdx.x;
    if (i < n) outExcl[i] += bsum[i >> 9];
}

// ---- pass B: LDS-staged partition by bucket, coalesced global writes ----
__global__ __launch_bounds__(256) void k_partition(
    const int* __restrict__ row, const int* __restrict__ col,
    const float* __restrict__ w, const int* __restrict__ scanExcl,
    int2* __restrict__ part) {
    __shared__ int2 stage[EPB];              // 32KB
    __shared__ unsigned short sbkt[EPB];     // 8KB
    __shared__ int cnt[NBKT];
    __shared__ int lofs[NBKT];
    __shared__ int cursor[NBKT];
    __shared__ int gbase[NBKT];
    __shared__ int sa[512], sb[512];
    int tid = threadIdx.x;
    long ebase = (long)blockIdx.x * EPB;
    int rr[EPT]; int cc[EPT]; float wv[EPT];
#pragma unroll
    for (int i = 0; i < EPT; i++) {
        long e = ebase + i * 256 + tid;
        if (e < NE) { rr[i] = row[e]; cc[i] = col[e]; wv[i] = w[e]; }
        else rr[i] = -1;
    }
    for (int i = tid; i < NBKT; i += 256) cnt[i] = 0;
    __syncthreads();
#pragma unroll
    for (int i = 0; i < EPT; i++)
        if (rr[i] >= 0) atomicAdd(&cnt[rr[i] >> 8], 1);
    __syncthreads();
    for (int i = tid; i < 512; i += 256) sa[i] = (i < NBKT) ? cnt[i] : 0;
    __syncthreads();
    int* src = sa; int* dst = sb;
    for (int off = 1; off < 512; off <<= 1) {
        for (int i = tid; i < 512; i += 256)
            dst[i] = src[i] + ((i >= off) ? src[i - off] : 0);
        __syncthreads();
        int* t = src; src = dst; dst = t;
    }
    for (int i = tid; i < NBKT; i += 256) {
        int ex = src[i] - cnt[i];
        lofs[i] = ex;
        cursor[i] = ex;
        gbase[i] = scanExcl[i * GP + blockIdx.x];
    }
    __syncthreads();
#pragma unroll
    for (int i = 0; i < EPT; i++) {
        if (rr[i] >= 0) {
            int b = rr[i] >> 8;
            int p = atomicAdd(&cursor[b], 1);
            int2 v;
            v.x = cc[i] | ((rr[i] & 255) << 17);
            v.y = __float_as_int(wv[i]);
            stage[p] = v;
            sbkt[p] = (unsigned short)b;
        }
    }
    __syncthreads();
    int total = (int)min((long)EPB, NE - ebase);
    for (int i = tid; i < total; i += 256) {
        int b = sbkt[i];
        part[gbase[b] + (i - lofs[b])] = stage[i];
    }
}

// ---- pass C: in-place per-bucket sort by row; emits rowptr AND dinv ----
__global__ __launch_bounds__(256) void k_bucket_sort(
    int2* __restrict__ part, const int* __restrict__ scanExcl,
    int* __restrict__ rowptr, float* __restrict__ dinv) {
    __shared__ int2 stage[CAP];          // 64KB
    __shared__ int hist[RB];
    __shared__ int cursor[RB];
    __shared__ int wtot[4];
    int b = blockIdx.x;
    int tid = threadIdx.x;
    int start = scanExcl[b * GP];
    int end = (b + 1 < NBKT) ? scanExcl[(b + 1) * GP] : NE;
    int count = end - start;
    hist[tid] = 0;
    __syncthreads();
    for (int i = tid; i < count; i += 256)
        atomicAdd(&hist[(part[start + i].x >> 17) & 255], 1);
    __syncthreads();
    int lane = tid & 63, wv = tid >> 6;
    int v = hist[tid];
    int sc = v;
#pragma unroll
    for (int off = 1; off < 64; off <<= 1) {
        int up = __shfl_up(sc, off, 64);
        if (lane >= off) sc += up;
    }
    if (lane == 63) wtot[wv] = sc;
    __syncthreads();
    int add = 0;
    for (int w2 = 0; w2 < wv; w2++) add += wtot[w2];
    int ex = sc + add - v;
    int node = b * RB + tid;
    if (node <= NN) rowptr[node] = start + ex;
    cursor[tid] = ex;
    __syncthreads();
    for (int i = tid; i < count; i += 256) {
        int2 p = part[start + i];
        int rl = (p.x >> 17) & 255;
        int pos = atomicAdd(&cursor[rl], 1);
        int2 c; c.x = p.x & 0x1FFFF; c.y = p.y;
        if (pos < CAP) stage[pos] = c;
    }
    __syncthreads();
    {
        int rend = cursor[tid];
        float d = 0.f;
        for (int i = ex; i < rend; i++) d += __int_as_float(stage[i].y);
        if (node < NN) dinv[node] = d > 0.f ? rsqrtf(d) : 0.f;
    }
    for (int i = tid; i < count; i += 256)
        if (i < CAP) part[start + i] = stage[i];
}

// part[j].w *= dinv[part[j].col]  (2 edges/thread, int4)
__global__ __launch_bounds__(256) void k_scalew(int2* __restrict__ part,
                                                const float* __restrict__ dinv) {
    long i = (long)blockIdx.x * 256 + threadIdx.x;
    if (i * 2 >= NE) return;
    int4* p4 = (int4*)part;
    int4 v = p4[i];
    v.y = __float_as_int(__int_as_float(v.y) * dinv[v.x]);
    v.w = __float_as_int(__int_as_float(v.w) * dinv[v.z]);
    p4[i] = v;
}

// xa = x@(W1_0-W1_1)+b1 (fp32) ; xb = x@W1_1 (fp8 e4m3).  1 thread = 1 node.
__global__ __launch_bounds__(256) void k_proj1(
    const float* __restrict__ x, const float* __restrict__ W0,
    const float* __restrict__ W1, const float* __restrict__ b1,
    float* __restrict__ xa, unsigned char* __restrict__ xb8) {
    __shared__ float xs[256 * 33];
    int tid = threadIdx.x;
    long nbase = (long)blockIdx.x * 256;
    float accA[HID], accB[HID];
#pragma unroll
    for (int o = 0; o < HID; o++) { accA[o] = 0.f; accB[o] = 0.f; }
    const float4* xg = (const float4*)x;
    for (int c = 0; c < 4; c++) {
#pragma unroll
        for (int i = 0; i < 8; i++) {
            int j = i * 256 + tid;
            int node = j >> 3, w4 = j & 7;
            long gn = nbase + node;
            float4 v = make_float4(0.f, 0.f, 0.f, 0.f);
            if (gn < NN) v = xg[gn * 32 + c * 8 + w4];
            int base = node * 33 + w4 * 4;
            xs[base + 0] = v.x; xs[base + 1] = v.y;
            xs[base + 2] = v.z; xs[base + 3] = v.w;
        }
        __syncthreads();
#pragma unroll 4
        for (int kk = 0; kk < 32; kk++) {
            float xk = xs[tid * 33 + kk];
            int k = c * 32 + kk;
#pragma unroll
            for (int o = 0; o < HID; o++) accA[o] += xk * W0[k * HID + o];
#pragma unroll
            for (int o = 0; o < HID; o++) accB[o] += xk * W1[k * HID + o];
        }
        __syncthreads();
    }
    long n = nbase + tid;
    if (n >= NN) return;
    float4* xap = (float4*)(xa + n * HID);
#pragma unroll
    for (int q = 0; q < 4; q++) {
        float4 va;
        va.x = accA[4*q+0] - accB[4*q+0] + b1[4*q+0];
        va.y = accA[4*q+1] - accB[4*q+1] + b1[4*q+1];
        va.z = accA[4*q+2] - accB[4*q+2] + b1[4*q+2];
        va.w = accA[4*q+3] - accB[4*q+3] + b1[4*q+3];
        xap[q] = va;
    }
    unsigned int pk[4];
#pragma unroll
    for (int q = 0; q < 4; q++)
        pk[q] = f2e4m3(accB[4*q+0]) | (f2e4m3(accB[4*q+1]) << 8)
              | (f2e4m3(accB[4*q+2]) << 16) | (f2e4m3(accB[4*q+3]) << 24);
    *(uint4*)(xb8 + n * HID) = make_uint4(pk[0], pk[1], pk[2], pk[3]);
}

// agg1[n,f] = dinv[n] * sum_j w'_j * xb[c_j,f].
// 1 wave = 1 node; lane = (parity p 0..7, feat-pair q 0..7); unroll 2.
__global__ __launch_bounds__(256) void k_gather1(
    const int* __restrict__ rowptr, const int2* __restrict__ part,
    const float* __restrict__ dinv, const unsigned char* __restrict__ xb8,
    float* __restrict__ agg1) {
    long t = (long)blockIdx.x * 256 + threadIdx.x;
    int n = (int)(t >> 6);
    if (n >= NN) return;
    int lane = threadIdx.x & 63;
    int q = lane & 7, p = lane >> 3;
    int s = rowptr[n], e = rowptr[n + 1];
    f32x2 acc = {0.f, 0.f};
    int j = s + p;
    for (; j + 8 < e; j += 16) {
        int2 e0 = part[j], e1 = part[j + 8];
        unsigned int b0 = *(const unsigned short*)(xb8 + e0.x * HID + q * 2);
        unsigned int b1 = *(const unsigned short*)(xb8 + e1.x * HID + q * 2);
        f32x2 v0 = fp8x2_to_f32(b0), v1 = fp8x2_to_f32(b1);
        float w0 = __int_as_float(e0.y), w1 = __int_as_float(e1.y);
        acc.x += w0 * v0.x + w1 * v1.x;
        acc.y += w0 * v0.y + w1 * v1.y;
    }
    if (j < e) {
        int2 e0 = part[j];
        unsigned int b0 = *(const unsigned short*)(xb8 + e0.x * HID + q * 2);
        f32x2 v0 = fp8x2_to_f32(b0);
        float w0 = __int_as_float(e0.y);
        acc.x += w0 * v0.x;
        acc.y += w0 * v0.y;
    }
    acc.x += __shfl_xor(acc.x, 8);  acc.y += __shfl_xor(acc.y, 8);
    acc.x += __shfl_xor(acc.x, 16); acc.y += __shfl_xor(acc.y, 16);
    acc.x += __shfl_xor(acc.x, 32); acc.y += __shfl_xor(acc.y, 32);
    if (p == 0) {
        float dn = dinv[n];
        f32x2 o; o.x = dn * acc.x; o.y = dn * acc.y;
        *(f32x2*)(agg1 + n * HID + q * 2) = o;
    }
}

// h = relu(xa+agg1); ha = h@(W2_0-W2_1)+b2 (fp32) ; hb = h@W2_1 (fp8 e4m3).
__global__ __launch_bounds__(256) void k_proj2(
    const float* __restrict__ xa, const float* __restrict__ agg1,
    const float* __restrict__ W0, const float* __restrict__ W1,
    const float* __restrict__ b2,
    float* __restrict__ ha, unsigned char* __restrict__ hb8) {
    long n = (long)blockIdx.x * 256 + threadIdx.x;
    if (n >= NN) return;
    float h[HID];
    const float4* xap = (const float4*)(xa + n * HID);
    const float4* agp = (const float4*)(agg1 + n * HID);
#pragma unroll
    for (int q = 0; q < 4; q++) {
        float4 a = xap[q], g = agp[q];
        h[4*q+0] = fmaxf(a.x + g.x, 0.f);
        h[4*q+1] = fmaxf(a.y + g.y, 0.f);
        h[4*q+2] = fmaxf(a.z + g.z, 0.f);
        h[4*q+3] = fmaxf(a.w + g.w, 0.f);
    }
    float accA[NCLS], accB[NCLS];
#pragma unroll
    for (int o = 0; o < NCLS; o++) { accA[o] = 0.f; accB[o] = 0.f; }
#pragma unroll 2
    for (int k = 0; k < HID; k++) {
        float hk = h[k];
#pragma unroll
        for (int o = 0; o < NCLS; o++) accA[o] += hk * W0[k * NCLS + o];
#pragma unroll
        for (int o = 0; o < NCLS; o++) accB[o] += hk * W1[k * NCLS + o];
    }
    float4* hap = (float4*)(ha + n * NCLS);
#pragma unroll
    for (int q = 0; q < 8; q++) {
        float4 va;
        va.x = accA[4*q+0] - accB[4*q+0] + b2[4*q+0];
        va.y = accA[4*q+1] - accB[4*q+1] + b2[4*q+1];
        va.z = accA[4*q+2] - accB[4*q+2] + b2[4*q+2];
        va.w = accA[4*q+3] - accB[4*q+3] + b2[4*q+3];
        hap[q] = va;
    }
    unsigned int pk[8];
#pragma unroll
    for (int q = 0; q < 8; q++)
        pk[q] = f2e4m3(accB[4*q+0]) | (f2e4m3(accB[4*q+1]) << 8)
              | (f2e4m3(accB[4*q+2]) << 16) | (f2e4m3(accB[4*q+3]) << 24);
    uint4* hbp = (uint4*)(hb8 + n * NCLS);
    hbp[0] = make_uint4(pk[0], pk[1], pk[2], pk[3]);
    hbp[1] = make_uint4(pk[4], pk[5], pk[6], pk[7]);
}

// out[n,:] = log_softmax(ha[n,:] + dinv[n]*sum_j w'_j*hb[c_j,:]).
// 1 wave = 1 node; lane = (parity p 0..3, class-pair q 0..15); unroll 2.
__global__ __launch_bounds__(256) void k_gather2_lsm(
    const int* __restrict__ rowptr, const int2* __restrict__ part,
    const float* __restrict__ dinv, const float* __restrict__ ha,
    const unsigned char* __restrict__ hb8, float* __restrict__ out) {
    long t = (long)blockIdx.x * 256 + threadIdx.x;
    int n = (int)(t >> 6);
    if (n >= NN) return;
    int lane = threadIdx.x & 63;
    int q = lane & 15, p = lane >> 4;
    int s = rowptr[n], e = rowptr[n + 1];
    f32x2 acc = {0.f, 0.f};
    int j = s + p;
    for (; j + 4 < e; j += 8) {
        int2 e0 = part[j], e1 = part[j + 4];
        unsigned int b0 = *(const unsigned short*)(hb8 + e0.x * NCLS + q * 2);
        unsigned int b1 = *(const unsigned short*)(hb8 + e1.x * NCLS + q * 2);
        f32x2 v0 = fp8x2_to_f32(b0), v1 = fp8x2_to_f32(b1);
        float w0 = __int_as_float(e0.y), w1 = __int_as_float(e1.y);
        acc.x += w0 * v0.x + w1 * v1.x;
        acc.y += w0 * v0.y + w1 * v1.y;
    }
    if (j < e) {
        int2 e0 = part[j];
        unsigned int b0 = *(const unsigned short*)(hb8 + e0.x * NCLS + q * 2);
        f32x2 v0 = fp8x2_to_f32(b0);
        float w0 = __int_as_float(e0.y);
        acc.x += w0 * v0.x;
        acc.y += w0 * v0.y;
    }
    acc.x += __shfl_xor(acc.x, 16); acc.y += __shfl_xor(acc.y, 16);
    acc.x += __shfl_xor(acc.x, 32); acc.y += __shfl_xor(acc.y, 32);
    float dn = dinv[n];
    f32x2 hv = *(const f32x2*)(ha + n * NCLS + q * 2);
    float vx = dn * acc.x + hv.x;
    float vy = dn * acc.y + hv.y;
    float m = fmaxf(vx, vy);
    m = fmaxf(m, __shfl_xor(m, 1));
    m = fmaxf(m, __shfl_xor(m, 2));
    m = fmaxf(m, __shfl_xor(m, 4));
    m = fmaxf(m, __shfl_xor(m, 8));
    float sum = __expf(vx - m) + __expf(vy - m);
    sum += __shfl_xor(sum, 1);
    sum += __shfl_xor(sum, 2);
    sum += __shfl_xor(sum, 4);
    sum += __shfl_xor(sum, 8);
    float ls = logf(sum);
    if (p == 0) {
        f32x2 o; o.x = vx - m - ls; o.y = vy - m - ls;
        *(f32x2*)(out + n * NCLS + q * 2) = o;
    }
}

extern "C" void kernel_launch(void* const* d_in, const int* in_sizes, int n_in,
                              void* d_out, int out_size, void* d_ws, size_t ws_size,
                              hipStream_t stream) {
    const float* x    = (const float*)d_in[0];
    const int*   ei   = (const int*)d_in[1];
    const float* ew   = (const float*)d_in[2];
    const float* W1_0 = (const float*)d_in[3];
    const float* W1_1 = (const float*)d_in[4];
    const float* b1   = (const float*)d_in[5];
    const float* W2_0 = (const float*)d_in[6];
    const float* W2_1 = (const float*)d_in[7];
    const float* b2   = (const float*)d_in[8];
    float* out = (float*)d_out;

    const int* row = ei;
    const int* col = ei + NE;

    char* ws = (char*)d_ws;
    int2*  part      = (int2*)ws;                 ws += sizeof(int2) * NE;
    int*   blockhist = (int*)ws;                  ws += sizeof(int) * NTOT;
    int*   scanExcl  = (int*)ws;                  ws += sizeof(int) * NTOT;
    int*   bsum      = (int*)ws;                  ws += sizeof(int) * 512;
    int*   rowptr    = (int*)ws;                  ws += sizeof(int) * (NN + 4);
    float* dinv      = (float*)ws;                ws += sizeof(float) * NN;
    float* xa        = (float*)ws;                ws += sizeof(float) * NN * HID;
    float* agg1      = (float*)ws;                ws += sizeof(float) * NN * HID;
    float* ha        = (float*)ws;                ws += sizeof(float) * NN * NCLS;
    unsigned char* xb8 = (unsigned char*)ws;      ws += sizeof(char) * NN * HID;
    unsigned char* hb8 = (unsigned char*)ws;      ws += sizeof(char) * NN * NCLS;

    k_hist<<<GP, 256, 0, stream>>>(row, blockhist);
    k_scan_block<<<NBS, SCAN_CHUNK, 0, stream>>>(blockhist, scanExcl, bsum, NTOT);
    k_scan_tops<<<1, 64, 0, stream>>>(bsum, NBS);
    k_scan_add<<<(NTOT + 255) / 256, 256, 0, stream>>>(scanExcl, bsum, NTOT);
    k_partition<<<GP, 256, 0, stream>>>(row, col, ew, scanExcl, part);
    k_bucket_sort<<<NBKT, 256, 0, stream>>>(part, scanExcl, rowptr, dinv);
    k_scalew<<<(NE / 2 + 255) / 256, 256, 0, stream>>>(part, dinv);
    k_proj1<<<(NN + 255) / 256, 256, 0, stream>>>(x, W1_0, W1_1, b1, xa, xb8);
    {
        long th = (long)NN * 64;
        k_gather1<<<(int)((th + 255) / 256), 256, 0, stream>>>(rowptr, part, dinv, xb8, agg1);
    }
    k_proj2<<<(NN + 255) / 256, 256, 0, stream>>>(xa, agg1, W2_0, W2_1, b2, ha, hb8);
    {
        long th = (long)NN * 64;
        k_gather2_lsm<<<(int)((th + 255) / 256), 256, 0, stream>>>(rowptr, part, dinv, ha, hb8, out);
    }
}